// Round 1
// baseline (5245.275 us; speedup 1.0000x reference)
//
#include <hip/hip_runtime.h>

#define PI_F     3.14159265358979323846f
#define TWOPI_F  6.28318530717958647692f
#define HPI_F    1.57079632679489661923f

constexpr int fftT(int N){ return N>=512 ? 256 : (N/2 < 64 ? 64 : N/2); }

__device__ __forceinline__ float fcoord(int k, int n){
  int s = k ^ (n>>1);
  return (float)(s - (n>>1)) / (float)(n>>1);
}
__device__ __forceinline__ float lograd(int kr, int kc, int n){
  if (kr==0 && kc==0) return log2f(2.0f/(float)n);
  float x = fcoord(kc,n), y = fcoord(kr,n);
  return 0.5f*log2f(x*x+y*y);
}
__device__ __forceinline__ float rc_sin(float lr, float shift){
  float t = fminf(fmaxf(lr+shift,0.f),1.f); return __sinf(HPI_F*t);
}
__device__ __forceinline__ float rc_cos(float lr, float shift){
  float t = fminf(fmaxf(lr+shift,0.f),1.f); return __cosf(HPI_F*t);
}
// oriented mask * him for scale of size n, band b   (order=3, const=0.8)
__device__ __forceinline__ float bandmask(int kr, int kc, int n, int b){
  float x = fcoord(kc,n), y = fcoord(kr,n);
  float ang = atan2f(y,x);
  float lr = lograd(kr,kc,n);
  float him = rc_sin(lr,2.0f);
  float th = ang - 0.25f*PI_F*(float)b;
  float u = th + PI_F;
  u -= TWOPI_F*floorf(u*(1.0f/TWOPI_F));
  float thw = u - PI_F;
  float c = __cosf(th);
  float am = (fabsf(thw) < HPI_F) ? (1.7888543819998317f*c*c*c) : 0.0f; // 2*sqrt(0.8)
  return am*him;
}

__device__ __forceinline__ void waveAccum(double* slot, float v){
  for (int o=32;o>0;o>>=1) v += __shfl_down(v,o);
  if ((threadIdx.x & 63)==0) atomicAdd(slot,(double)v);
}

// ---------------- FFT: radix-2 Stockham in LDS, one block per row -------------
template<int N>
__global__ void k_fft_rows(const float2* __restrict__ src, float2* __restrict__ dst,
                           const float* __restrict__ rsrc, float dirsign, float scale){
  constexpr int T = fftT(N);
  __shared__ float2 sm[2][N];
  const int row = blockIdx.x;
  const int tid = threadIdx.x;
  if (rsrc){
    const float* rp = rsrc + (size_t)row*N;
    for (int i=tid;i<N;i+=T) sm[0][i] = make_float2(rp[i],0.f);
  } else {
    const float2* sp = src + (size_t)row*N;
    for (int i=tid;i<N;i+=T) sm[0][i] = sp[i];
  }
  int cur = 0;
  for (int ls=0; (1<<ls) < N; ++ls){
    const int Ns = 1<<ls;
    __syncthreads();
    for (int j=tid; j<N/2; j+=T){
      const int m = j & (Ns-1);
      const int base = ((j>>ls)<<(ls+1)) + m;
      float2 a = sm[cur][j];
      float2 b = sm[cur][j + N/2];
      float ang = dirsign * (TWOPI_F * (float)m / (float)(2*Ns));
      float sn, cs;
      __sincosf(ang,&sn,&cs);
      float2 bw = make_float2(b.x*cs - b.y*sn, b.x*sn + b.y*cs);
      sm[cur^1][base]    = make_float2(a.x+bw.x, a.y+bw.y);
      sm[cur^1][base+Ns] = make_float2(a.x-bw.x, a.y-bw.y);
    }
    cur ^= 1;
  }
  __syncthreads();
  float2* dp = dst + (size_t)row*N;
  for (int i=tid;i<N;i+=T){ float2 v=sm[cur][i]; dp[i]=make_float2(v.x*scale, v.y*scale); }
}

__global__ void k_transpose(const float2* __restrict__ src, float2* __restrict__ dst, int n){
  __shared__ float2 t[32][33];
  int bx = blockIdx.x*32, by = blockIdx.y*32;
  for (int dy=threadIdx.y; dy<32; dy+=8)
    t[dy][threadIdx.x] = src[(size_t)(by+dy)*n + bx + threadIdx.x];
  __syncthreads();
  for (int dy=threadIdx.y; dy<32; dy+=8)
    dst[(size_t)(bx+dy)*n + by + threadIdx.x] = t[threadIdx.x][dy];
}

// ---------------- elementwise / mask kernels ---------------------------------
__global__ void k_init(double* S, unsigned* SU, float* out, int nout){
  int i = blockIdx.x*blockDim.x + threadIdx.x;
  if (i < 400) S[i]=0.0;
  if (i==0){ SU[0]=0xFFFFFFFFu; SU[1]=0u; }
  if (i < nout) out[i]=0.f;
}

__global__ void k_imgstats1(const float* __restrict__ x, int n, double* S, unsigned* SU){
  int stride = gridDim.x*blockDim.x;
  float s=0.f, mn=3.4e38f, mx=-3.4e38f;
  for (int i=blockIdx.x*blockDim.x+threadIdx.x; i<n; i+=stride){
    float v=x[i]; s+=v; mn=fminf(mn,v); mx=fmaxf(mx,v);
  }
  waveAccum(S+0, s);
  for (int o=32;o>0;o>>=1){ mn=fminf(mn,__shfl_down(mn,o)); mx=fmaxf(mx,__shfl_down(mx,o)); }
  if ((threadIdx.x&63)==0){
    unsigned em=__float_as_uint(mn); em=(em>>31)? ~em : (em|0x80000000u);
    unsigned eM=__float_as_uint(mx); eM=(eM>>31)? ~eM : (eM|0x80000000u);
    atomicMin(SU+0, em); atomicMax(SU+1, eM);
  }
}
__global__ void k_imgstats2(const float* __restrict__ x, int n, double* S){
  float mean = (float)(S[0]/(double)n);
  int stride = gridDim.x*blockDim.x;
  float s2=0,s3=0,s4=0;
  for (int i=blockIdx.x*blockDim.x+threadIdx.x; i<n; i+=stride){
    float d=x[i]-mean, d2=d*d; s2+=d2; s3+=d2*d; s4+=d2*d2;
  }
  waveAccum(S+1,s2); waveAccum(S+2,s3); waveAccum(S+3,s4);
}

__global__ void k_split(const float2* __restrict__ F, float2* HI, float2* LOD, int n, int lg){
  int idx = blockIdx.x*blockDim.x+threadIdx.x;
  int kr = idx>>lg, kc = idx&(n-1);
  float lr = lograd(kr,kc,n);
  float s = rc_sin(lr,1.f), c = rc_cos(lr,1.f);
  float2 v = F[idx];
  HI[idx]  = make_float2(v.x*s, v.y*s);
  LOD[idx] = make_float2(v.x*c, v.y*c);
}
__global__ void k_bdft(const float2* __restrict__ LOD, float2* out, int n, int lg, int b){
  int idx = blockIdx.x*blockDim.x+threadIdx.x;
  int kr = idx>>lg, kc = idx&(n-1);
  float m = bandmask(kr,kc,n,b);
  float2 v = LOD[idx];
  out[idx] = make_float2(-v.y*m, v.x*m);   // (-1j)^3 = +i rotation
}
__global__ void k_unorspec(const float2* __restrict__ LOD, float2* U, float2* P, int n, int lg){
  int idx = blockIdx.x*blockDim.x+threadIdx.x;
  int kr = idx>>lg, kc = idx&(n-1);
  float him = rc_sin(lograd(kr,kc,n),2.f);
  float2 v = LOD[idx];
  float ur=v.x*him, ui=v.y*him;
  U[idx]=make_float2(ur,ui);
  P[idx]=make_float2(ur*ur+ui*ui,0.f);
}
__global__ void k_croplo(const float2* __restrict__ src, float2* dst, int nn, int lgn){
  int idx = blockIdx.x*blockDim.x+threadIdx.x;
  int kr = idx>>lgn, kc = idx&(nn-1);
  int h = nn>>1;
  int sr = (kr<h)?kr:kr+nn;
  int sc = (kc<h)?kc:kc+nn;
  float lom = rc_cos(lograd(kr,kc,nn),1.f);
  float2 v = src[(size_t)sr*(2*nn)+sc];
  dst[idx] = make_float2(v.x*lom, v.y*lom);
}
__global__ void k_padband(const float2* __restrict__ LODc, float2* dst, int n, int lg, int b){
  int idx = blockIdx.x*blockDim.x+threadIdx.x;
  int kr = idx>>lg, kc = idx&(n-1);
  int m=n>>1, q=m>>1;
  int sr = (kr<q)?kr : (kr>=n-q ? kr-m : -1);
  int sc = (kc<q)?kc : (kc>=n-q ? kc-m : -1);
  float2 r = make_float2(0.f,0.f);
  if (sr>=0 && sc>=0){
    float msk = bandmask(sr,sc,m,b);
    float2 v = LODc[(size_t)sr*m+sc];
    r = make_float2(-v.y*msk, v.x*msk);
  }
  dst[idx]=r;
}
__global__ void k_padlp(const float2* __restrict__ LODc, float2* dst, int n, int lg){
  int idx = blockIdx.x*blockDim.x+threadIdx.x;
  int kr = idx>>lg, kc = idx&(n-1);
  int m=n>>1, q=m>>1;
  int sr = (kr<q)?kr : (kr>=n-q ? kr-m : -1);
  int sc = (kc<q)?kc : (kc>=n-q ? kc-m : -1);
  float2 r = make_float2(0.f,0.f);
  if (sr>=0 && sc>=0 && !(sr==0&&sc==0)) r = LODc[(size_t)sr*m+sc];
  dst[idx]=r;
}
__global__ void k_imlpspec(const float2* __restrict__ LOD4, float2* U, float2* P, int n, int lg){
  int idx = blockIdx.x*blockDim.x+threadIdx.x;
  int kr = idx>>lg, kc = idx&(n-1);
  float lo = rc_cos(lograd(kr,kc,n),1.f);
  float2 v = LOD4[idx];
  if (idx==0){ v.x=0.f; v.y=0.f; }
  float ur=v.x*lo, ui=v.y*lo;
  U[idx]=make_float2(ur,ui);
  P[idx]=make_float2(ur*ur+ui*ui,0.f);
}
__global__ void k_power(float2* buf, int zero_dc){
  int idx = blockIdx.x*blockDim.x+threadIdx.x;
  float2 v=buf[idx];
  float p=v.x*v.x+v.y*v.y;
  if (zero_dc && idx==0) p=0.f;
  buf[idx]=make_float2(p,0.f);
}

// ---------------- reductions --------------------------------------------------
__global__ void k_extract(const float2* __restrict__ band, float* mag, float* re, int n2, double* slot){
  int stride = gridDim.x*blockDim.x;
  float acc=0.f;
  for (int i=blockIdx.x*blockDim.x+threadIdx.x; i<n2; i+=stride){
    float2 v=band[i];
    float m=sqrtf(v.x*v.x+v.y*v.y);
    mag[i]=m; re[i]=v.x; acc+=m;
  }
  waveAccum(slot,acc);
}
__global__ void k_abssq(const float2* __restrict__ buf, int n2, double* slots){
  int stride = gridDim.x*blockDim.x;
  float a1=0,a2=0;
  for (int i=blockIdx.x*blockDim.x+threadIdx.x; i<n2; i+=stride){
    float v=buf[i].x; a1+=fabsf(v); a2+=v*v;
  }
  waveAccum(slots+0,a1); waveAccum(slots+1,a2);
}
__global__ void k_mom234(const float2* __restrict__ buf, int n2, double* slots){
  int stride = gridDim.x*blockDim.x;
  float s2=0,s3=0,s4=0;
  for (int i=blockIdx.x*blockDim.x+threadIdx.x; i<n2; i+=stride){
    float v=buf[i].x, v2=v*v; s2+=v2; s3+=v2*v; s4+=v2*v2;
  }
  waveAccum(slots+0,s2); waveAccum(slots+1,s3); waveAccum(slots+2,s4);
}
__global__ void k_sumreal(const float2* __restrict__ buf, int n2, double* slot){
  int stride = gridDim.x*blockDim.x;
  float s=0;
  for (int i=blockIdx.x*blockDim.x+threadIdx.x; i<n2; i+=stride) s+=buf[i].x;
  waveAccum(slot,s);
}
__global__ void k_lpabs(const float2* __restrict__ buf, int n2, double* S){
  float mu = (float)(S[22]/(double)n2);
  int stride = gridDim.x*blockDim.x;
  float s=0;
  for (int i=blockIdx.x*blockDim.x+threadIdx.x; i<n2; i+=stride) s+=fabsf(buf[i].x-mu);
  waveAccum(S+23,s);
}
__global__ void k_gram(const float* __restrict__ mag, const float* __restrict__ re, int n2, double* slots){
  float p[20];
  #pragma unroll
  for (int i=0;i<20;i++) p[i]=0.f;
  int stride = gridDim.x*blockDim.x;
  for (int i=blockIdx.x*blockDim.x+threadIdx.x; i<n2; i+=stride){
    float m0=mag[i], m1=mag[i+(size_t)n2], m2=mag[i+2*(size_t)n2], m3=mag[i+3*(size_t)n2];
    float r0=re[i],  r1=re[i+(size_t)n2],  r2=re[i+2*(size_t)n2],  r3=re[i+3*(size_t)n2];
    p[0]+=m0*m0; p[1]+=m0*m1; p[2]+=m0*m2; p[3]+=m0*m3;
    p[4]+=m1*m1; p[5]+=m1*m2; p[6]+=m1*m3;
    p[7]+=m2*m2; p[8]+=m2*m3; p[9]+=m3*m3;
    p[10]+=r0*r0; p[11]+=r0*r1; p[12]+=r0*r2; p[13]+=r0*r3;
    p[14]+=r1*r1; p[15]+=r1*r2; p[16]+=r1*r3;
    p[17]+=r2*r2; p[18]+=r2*r3; p[19]+=r3*r3;
  }
  #pragma unroll
  for (int k=0;k<20;k++) waveAccum(slots+k, p[k]);
}
__global__ void k_parentred(const float2* __restrict__ par, const float* __restrict__ mag,
                            const float* __restrict__ re, int n2, double* slots){
  float a[13];
  #pragma unroll
  for (int i=0;i<13;i++) a[i]=0.f;
  int stride = gridDim.x*blockDim.x;
  for (int i=blockIdx.x*blockDim.x+threadIdx.x; i<n2; i+=stride){
    float2 p = par[i];
    float pr=p.x, pi=p.y;
    float m = sqrtf(pr*pr+pi*pi);
    float rp=0.f, ip=0.f;
    if (m>0.f){ rp=(pi*pi-pr*pr)/m; ip=2.f*pr*pi/m; }
    a[0]+=m;
    a[1]+=mag[i]*m; a[2]+=mag[i+(size_t)n2]*m; a[3]+=mag[i+2*(size_t)n2]*m; a[4]+=mag[i+3*(size_t)n2]*m;
    a[5]+=re[i]*rp; a[6]+=re[i+(size_t)n2]*rp; a[7]+=re[i+2*(size_t)n2]*rp; a[8]+=re[i+3*(size_t)n2]*rp;
    a[9]+=re[i]*ip; a[10]+=re[i+(size_t)n2]*ip; a[11]+=re[i+2*(size_t)n2]*ip; a[12]+=re[i+3*(size_t)n2]*ip;
  }
  #pragma unroll
  for (int k=0;k<13;k++) waveAccum(slots+k, a[k]);
}
__global__ void k_rpext(const float2* __restrict__ buf, float* R, int n2){
  int stride = gridDim.x*blockDim.x;
  for (int i=blockIdx.x*blockDim.x+threadIdx.x; i<n2; i+=stride) R[i]=buf[i].x;
}
// last-scale: rcous is .T.ravel(), rparents is .ravel() -> transposed pairing
__global__ void k_crx3(const float* __restrict__ RP, const float* __restrict__ re, double* S){
  float a[35];
  #pragma unroll
  for (int i=0;i<35;i++) a[i]=0.f;
  int stride = gridDim.x*blockDim.x;
  for (int idx=blockIdx.x*blockDim.x+threadIdx.x; idx<16384; idx+=stride){
    int u=idx>>7, v=idx&127;
    float P0=RP[idx];
    float P1=RP[(u<<7) | ((v-1)&127)];
    float P2=RP[(u<<7) | ((v+1)&127)];
    float P3=RP[(((u-1)&127)<<7) | v];
    float P4=RP[(((u+1)&127)<<7) | v];
    float P[5]={P0,P1,P2,P3,P4};
    float R[4];
    #pragma unroll
    for (int b=0;b<4;b++) R[b]=re[b*16384 + (v<<7) + u];  // transposed read
    #pragma unroll
    for (int i=0;i<4;i++)
      #pragma unroll
      for (int j=0;j<5;j++) a[i*5+j]+=R[i]*P[j];
    int k=20;
    #pragma unroll
    for (int i=0;i<5;i++)
      #pragma unroll
      for (int j=i;j<5;j++){ a[k]+=P[i]*P[j]; k++; }
  }
  #pragma unroll
  for (int k=0;k<20;k++) waveAccum(S+280+k, a[k]);
  #pragma unroll
  for (int k=0;k<15;k++) waveAccum(S+300+k, a[20+k]);
}
// gather 9x9 autocorr window, wrapping, from (optionally transposed) ifft2 result
__global__ void k_gather(const float2* __restrict__ src, int n, float scale, int transposed,
                         float* dst, int stride){
  int t = threadIdx.x;
  if (t>=81) return;
  int i=t/9, j=t%9;
  int a=(i-4)&(n-1), b=(j-4)&(n-1);
  int r = transposed? b:a, c = transposed? a:b;
  dst[t*stride] = src[(size_t)r*n+c].x * scale;
}

__global__ void k_final(const double* S, const unsigned* SU, float* out){
  if (threadIdx.x || blockIdx.x) return;
  const double N0 = 1048576.0;
  double npix[4]={1048576.0,262144.0,65536.0,16384.0};
  double mean0 = S[0]/N0;
  double var0  = S[1]/(N0-1.0);
  out[0]=(float)mean0; out[1]=(float)var0;
  out[2]=(float)((S[2]/N0)/(var0*sqrt(var0)));
  out[3]=(float)((S[3]/N0)/(var0*var0));
  unsigned em=SU[0], eM=SU[1];
  em = (em&0x80000000u)? (em&0x7FFFFFFFu) : ~em;
  eM = (eM&0x80000000u)? (eM&0x7FFFFFFFu) : ~eM;
  out[4]=__uint_as_float(em); out[5]=__uint_as_float(eM);
  out[6]=(float)(S[4]/N0);
  for (int s=0;s<4;s++) for (int b=0;b<4;b++) out[7+s*4+b]=(float)(S[6+s*4+b]/npix[s]);
  out[23]=(float)(S[23]/4096.0);
  for (int s=0;s<4;s++){
    double n2=npix[s];
    double vari = S[24+s*3]/(2.0*n2);
    int ok = (vari/var0 > 1e-6);
    out[1320+s] = ok? (float)(0.5*(S[25+s*3]/n2)/(vari*sqrt(vari))) : 0.f;
    out[1325+s] = ok? (float)(0.5*(S[26+s*3]/n2)/(vari*vari)) : 3.f;
  }
  { double vari=S[36]/4096.0; int ok=(vari/var0>1e-6);
    out[1324] = ok? (float)((S[37]/4096.0)/(vari*sqrt(vari))) : 0.f;
    out[1329] = ok? (float)((S[38]/4096.0)/(vari*vari)) : 3.f;
  }
  for (int s=0;s<4;s++){
    double n2=npix[s];
    const double* G = S+40+s*20;
    for (int i=0;i<4;i++) for (int j=0;j<4;j++){
      int a = i<j?i:j, bb = i<j?j:i;
      int p = a*(7-a)/2 + bb;
      double Si=S[6+s*4+i], Sj=S[6+s*4+j];
      out[1735 + (i*4+j)*5 + s] = (float)((G[p] - Si*Sj/n2)/n2);
      out[1879 + (i*8+j)*5 + s] = (float)(G[10+p]/n2);
    }
  }
  for (int s=0;s<3;s++){
    double n2=npix[s];
    for (int j=0;j<4;j++){
      const double* P = S+120+(s*4+j)*13;
      double Smj=P[0];
      for (int i=0;i<4;i++){
        double Si=S[6+s*4+i];
        out[1815 + (i*4+j)*4 + s]     = (float)((P[1+i] - Si*Smj/n2)/n2);
        out[2199 + (i*8+j)*4 + s]     = (float)(P[5+i]/n2);
        out[2199 + (i*8+(j+4))*4 + s] = (float)(P[9+i]/n2);
      }
    }
  }
  for (int i=0;i<4;i++) for (int j=0;j<5;j++)
    out[2199 + (i*8+j)*4 + 3] = (float)(S[280+i*5+j]/16384.0);
  for (int i=0;i<5;i++) for (int j=0;j<5;j++){
    int a = i<j?i:j, bb = i<j?j:i;
    int p = a*(9-a)/2 + bb;
    out[1879 + (i*8+j)*5 + 4] = (float)(S[300+p]/4096.0);
  }
  out[2455]=(float)(S[5]/N0);
}

// ---------------- host orchestration -----------------------------------------
static void rowfft(int n, int nrows, const float2* src, float2* dst, const float* rsrc,
                   int inv, hipStream_t st){
  float dir = inv? 1.f : -1.f;
  float scale = inv? 1.f/(float)n : 1.f;
  switch(n){
    case 1024: k_fft_rows<1024><<<dim3(nrows),dim3(fftT(1024)),0,st>>>(src,dst,rsrc,dir,scale); break;
    case 512:  k_fft_rows<512 ><<<dim3(nrows),dim3(fftT(512 )),0,st>>>(src,dst,rsrc,dir,scale); break;
    case 256:  k_fft_rows<256 ><<<dim3(nrows),dim3(fftT(256 )),0,st>>>(src,dst,rsrc,dir,scale); break;
    case 128:  k_fft_rows<128 ><<<dim3(nrows),dim3(fftT(128 )),0,st>>>(src,dst,rsrc,dir,scale); break;
    case 64:   k_fft_rows<64  ><<<dim3(nrows),dim3(fftT(64  )),0,st>>>(src,dst,rsrc,dir,scale); break;
  }
}
static void tr(const float2* s, float2* d, int n, hipStream_t st){
  k_transpose<<<dim3(n/32,n/32),dim3(32,8),0,st>>>(s,d,n);
}
static inline int rb(int n2){ int b=(n2+255)/256; return b>512?512:b; }
static inline dim3 ew(int n){ return dim3(n*n/256); }

extern "C" void kernel_launch(void* const* d_in, const int* in_sizes, int n_in,
                              void* d_out, int out_size, void* d_ws, size_t ws_size,
                              hipStream_t stream){
  const float* im = (const float*)d_in[0];
  float* out = (float*)d_out;
  char* w = (char*)d_ws;
  float2* CA = (float2*)(w);
  float2* CB = (float2*)(w + ((size_t)8<<20));
  float2* CC = (float2*)(w + ((size_t)16<<20));
  size_t off = (size_t)24<<20;
  float2* LOD[5]; int lsz[5]={1024,512,256,128,64};
  for (int i=0;i<5;i++){ LOD[i]=(float2*)(w+off); off += (size_t)lsz[i]*lsz[i]*8; }
  float* MAG = (float*)(w+off); off += (size_t)4*1024*1024*4;
  float* RE  = (float*)(w+off); off += (size_t)4*1024*1024*4;
  float* R1  = (float*)(w+off); off += 128*128*4;
  double* S  = (double*)(w+off);
  unsigned* SU = (unsigned*)(w+off+3200);

  k_init<<<10,256,0,stream>>>(S,SU,out,2456);
  k_imgstats1<<<512,256,0,stream>>>(im,1024*1024,S,SU);
  k_imgstats2<<<512,256,0,stream>>>(im,1024*1024,S);

  // imdft (unshifted) -> CA
  rowfft(1024,1024,nullptr,CA,im,0,stream);
  tr(CA,CB,1024,stream);
  rowfft(1024,1024,CB,CB,nullptr,0,stream);
  tr(CB,CA,1024,stream);
  // split into hi0-dft (CB) and lodft0
  k_split<<<ew(1024),256,0,stream>>>(CA,CB,LOD[0],1024,10);
  // hi0 (orientation-free reductions -> 3-launch)
  rowfft(1024,1024,CB,CB,nullptr,1,stream);
  tr(CB,CC,1024,stream);
  rowfft(1024,1024,CC,CC,nullptr,1,stream);
  k_abssq<<<rb(1024*1024),256,0,stream>>>(CC,1024*1024,S+4);

  for (int s=0;s<4;s++){
    int n = 1024>>s, lg = 10-s, n2=n*n;
    // ---- bands: synthesize, extract mag/re ----
    for (int b=0;b<4;b++){
      k_bdft<<<ew(n),256,0,stream>>>(LOD[s],CA,n,lg,b);
      rowfft(n,n,CA,CA,nullptr,1,stream);
      tr(CA,CB,n,stream);
      rowfft(n,n,CB,CB,nullptr,1,stream);
      tr(CB,CA,n,stream);
      k_extract<<<rb(n2),256,0,stream>>>(CA, MAG+(size_t)b*n2, RE+(size_t)b*n2, n2, S+6+s*4+b);
    }
    k_gram<<<rb(n2),256,0,stream>>>(MAG,RE,n2,S+40+s*20);
    // ---- ace: autocorr of magnitudes ----
    for (int b=0;b<4;b++){
      rowfft(n,n,nullptr,CA,MAG+(size_t)b*n2,0,stream);
      tr(CA,CB,n,stream);
      rowfft(n,n,CB,CB,nullptr,0,stream);
      k_power<<<ew(n),256,0,stream>>>(CB,1);
      rowfft(n,n,CB,CB,nullptr,1,stream);
      tr(CB,CA,n,stream);
      rowfft(n,n,CA,CA,nullptr,1,stream);
      k_gather<<<1,128,0,stream>>>(CA,n,1.f/(float)n2,0,out+24+s*4+b,16);
    }
    // ---- unor + acr ----
    k_unorspec<<<ew(n),256,0,stream>>>(LOD[s],CA,CB,n,lg);
    rowfft(n,n,CA,CA,nullptr,1,stream);
    tr(CA,CC,n,stream);
    rowfft(n,n,CC,CC,nullptr,1,stream);
    k_mom234<<<rb(n2),256,0,stream>>>(CC,n2,S+24+s*3);
    rowfft(n,n,CB,CB,nullptr,1,stream);
    tr(CB,CA,n,stream);
    rowfft(n,n,CA,CA,nullptr,1,stream);
    k_gather<<<1,128,0,stream>>>(CA,n,1.f/(2.f*(float)n2),1,out+1330+s,5);
    // ---- next lodft ----
    int nn=n>>1;
    k_croplo<<<ew(nn),256,0,stream>>>(LOD[s],LOD[s+1],nn,lg-1);
    if (s<3){
      // ---- parents: expand next-scale bands to this scale ----
      for (int b=0;b<4;b++){
        k_padband<<<ew(n),256,0,stream>>>(LOD[s+1],CB,n,lg,b);
        rowfft(n,n,CB,CB,nullptr,1,stream);
        tr(CB,CA,n,stream);
        rowfft(n,n,CA,CA,nullptr,1,stream);
        tr(CA,CB,n,stream);
        k_parentred<<<rb(n2),256,0,stream>>>(CB,MAG,RE,n2,S+120+(s*4+b)*13);
      }
    } else {
      // ---- lowpass ----
      rowfft(64,64,LOD[4],CA,nullptr,1,stream);
      tr(CA,CB,64,stream);
      rowfft(64,64,CB,CB,nullptr,1,stream);
      k_sumreal<<<rb(4096),256,0,stream>>>(CB,4096,S+22);
      k_lpabs<<<rb(4096),256,0,stream>>>(CB,4096,S);
      // ---- imlp ----
      k_imlpspec<<<ew(64),256,0,stream>>>(LOD[4],CA,CC,64,6);
      rowfft(64,64,CA,CA,nullptr,1,stream);
      tr(CA,CB,64,stream);
      rowfft(64,64,CB,CB,nullptr,1,stream);
      k_mom234<<<rb(4096),256,0,stream>>>(CB,4096,S+36);
      rowfft(64,64,CC,CC,nullptr,1,stream);
      tr(CC,CA,64,stream);
      rowfft(64,64,CA,CA,nullptr,1,stream);
      k_gather<<<1,128,0,stream>>>(CA,64,1.f/4096.f,1,out+1334,5);
      // ---- rparents from expanded lowpass ----
      k_padlp<<<ew(128),256,0,stream>>>(LOD[4],CB,128,7);
      rowfft(128,128,CB,CB,nullptr,1,stream);
      tr(CB,CA,128,stream);
      rowfft(128,128,CA,CA,nullptr,1,stream);
      tr(CA,CB,128,stream);
      k_rpext<<<rb(16384),256,0,stream>>>(CB,R1,16384);
      k_crx3<<<64,256,0,stream>>>(R1,RE,S);
    }
  }
  k_final<<<1,64,0,stream>>>(S,SU,out);
  (void)in_sizes; (void)n_in; (void)out_size; (void)ws_size;
}

// Round 2
// 952.428 us; speedup vs baseline: 5.5073x; 5.5073x over previous
//
#include <hip/hip_runtime.h>

#define PI_F     3.14159265358979323846f
#define TWOPI_F  6.28318530717958647692f
#define HPI_F    1.57079632679489661923f

constexpr int fftT(int N){ return N>=512 ? 256 : (N/2 < 64 ? 64 : N/2); }

// S-slot layout (doubles)
#define SL_ACE 340          // 16 x 41
#define SL_ACR 996          // 4 x 41
#define SL_ALP 1160         // 41
#define SL_TOT 1280

__device__ __forceinline__ float fcoord(int k, int n){
  int s = k ^ (n>>1);
  return (float)(s - (n>>1)) / (float)(n>>1);
}
__device__ __forceinline__ float lograd(int kr, int kc, int n){
  if (kr==0 && kc==0) return log2f(2.0f/(float)n);
  float x = fcoord(kc,n), y = fcoord(kr,n);
  return 0.5f*log2f(x*x+y*y);
}
__device__ __forceinline__ float rc_sin(float lr, float shift){
  float t = fminf(fmaxf(lr+shift,0.f),1.f); return __sinf(HPI_F*t);
}
__device__ __forceinline__ float rc_cos(float lr, float shift){
  float t = fminf(fmaxf(lr+shift,0.f),1.f); return __cosf(HPI_F*t);
}
// oriented mask * him, order=3, const=0.8.  kr,kc are ORIGINAL freq indices.
__device__ __forceinline__ float bandmask(int kr, int kc, int n, int b){
  float x = fcoord(kc,n), y = fcoord(kr,n);
  float ang = atan2f(y,x);
  float lr = lograd(kr,kc,n);
  float him = rc_sin(lr,2.0f);
  float th = ang - 0.25f*PI_F*(float)b;
  float u = th + PI_F;
  u -= TWOPI_F*floorf(u*(1.0f/TWOPI_F));
  float thw = u - PI_F;
  float c = __cosf(th);
  float am = (fabsf(thw) < HPI_F) ? (1.7888543819998317f*c*c*c) : 0.0f;
  return am*him;
}
__device__ __forceinline__ int lagIdx(int di, int dj){
  if (dj < 0 || (dj==0 && di<0)){ di=-di; dj=-dj; }
  return dj==0 ? 36+di : (dj-1)*9 + (di+4);
}

__device__ __forceinline__ void waveAccum(double* slot, float v){
  for (int o=32;o>0;o>>=1) v += __shfl_down(v,o);
  if ((threadIdx.x & 63)==0) atomicAdd(slot,(double)v);
}
// block-level multi-slot reduce then atomics; red must hold NS*(blockDim/64) floats
template<int NS>
__device__ __forceinline__ void blockAccumN(double* base, const float* vals, float* red){
  const int lane = threadIdx.x & 63, wid = threadIdx.x >> 6;
  const int nw = (int)(blockDim.x >> 6);
  #pragma unroll
  for (int k=0;k<NS;k++){
    float v = vals[k];
    #pragma unroll
    for (int o=32;o>0;o>>=1) v += __shfl_down(v,o);
    if (lane==0) red[k*nw+wid]=v;
  }
  __syncthreads();
  if ((int)threadIdx.x < NS){
    float s=0.f;
    for (int w2=0;w2<nw;w2++) s += red[(int)threadIdx.x*nw+w2];
    atomicAdd(base+(int)threadIdx.x,(double)s);
  }
  __syncthreads();
}

// ---------------- fused FFT kernel ------------------------------------------
// PRE: 0 cplx row, 1 real row, 2 bandmask from LOD^T, 3 him mask, 4 padband,
//      5 padlp, 7 imlp mask, 9 split (hi to LDS, lo0 to aux2)
// POST: 0 store, 1 sum|x|,x^2 (no store), 2 store+sum mag, 3 store+moments,
//       4 parentred vs aux (no store)
struct FArgs {
  const float2* src; float2* dst;
  const float* rsrc;
  const float2* aux;      // CA4 for POST=4
  float2* aux2;           // LOD0 out for PRE=9
  double* slots;
  float dirsign, scale;
  int b0;
};

template<int N, int PRE, int POST>
__global__ __launch_bounds__(fftT(N)) void k_fft(FArgs a){
  constexpr int T = fftT(N);
  __shared__ float2 sm[2][N];
  const int row = blockIdx.x;
  const int img = blockIdx.y;
  const int tid = threadIdx.x;
  bool zrow = false;

  if constexpr (PRE==1){
    const float* rp = a.rsrc + (size_t)row*N;
    for (int i=tid;i<N;i+=T) sm[0][i] = make_float2(rp[i],0.f);
  } else if constexpr (PRE==0){
    const float2* sp = a.src + (size_t)img*N*N + (size_t)row*N;
    for (int i=tid;i<N;i+=T) sm[0][i] = sp[i];
  } else if constexpr (PRE==2){           // LOD^T storage: (row,i) = orig (kr=i,kc=row)
    const float2* sp = a.src + (size_t)row*N;
    const int b = a.b0 + img;
    for (int i=tid;i<N;i+=T){
      float2 v = sp[i];
      float m = bandmask(i, row, N, b);
      sm[0][i] = make_float2(-v.y*m, v.x*m);  // (-1j)^3 = +i
    }
  } else if constexpr (PRE==3){
    const float2* sp = a.src + (size_t)row*N;
    for (int i=tid;i<N;i+=T){
      float2 v = sp[i];
      float him = rc_sin(lograd(i,row,N),2.f);
      sm[0][i] = make_float2(v.x*him, v.y*him);
    }
  } else if constexpr (PRE==4 || PRE==5){ // pad from LOD^T of size N/2
    constexpr int M = N/2, Q = N/4;
    const int fi = (row<Q)? row : (row>=N-Q ? row-M : -1);
    if (fi < 0){
      for (int i=tid;i<N;i+=T) sm[0][i]=make_float2(0.f,0.f);
      zrow = true;
    } else {
      const float2* sp = a.src + (size_t)fi*M;
      const int b = a.b0 + img;
      for (int i=tid;i<N;i+=T){
        int fj = (i<Q)? i : (i>=N-Q ? i-M : -1);
        float2 r = make_float2(0.f,0.f);
        if (fj>=0){
          float2 v = sp[fj];
          if constexpr (PRE==4){
            float m = bandmask(fj, fi, M, b);
            r = make_float2(-v.y*m, v.x*m);
          } else {
            if (!(fi==0 && fj==0)) r = v;
          }
        }
        sm[0][i] = r;
      }
    }
  } else if constexpr (PRE==7){
    const float2* sp = a.src + (size_t)row*N;
    for (int i=tid;i<N;i+=T){
      float2 v = sp[i];
      if (row==0 && i==0) v = make_float2(0.f,0.f);
      float lo = rc_cos(lograd(i,row,N),1.f);
      sm[0][i] = make_float2(v.x*lo, v.y*lo);
    }
  } else if constexpr (PRE==9){
    const float2* sp = a.src + (size_t)row*N;
    float2* lp = a.aux2 + (size_t)row*N;
    for (int i=tid;i<N;i+=T){
      float2 v = sp[i];
      float lr = lograd(i,row,N);
      float s = rc_sin(lr,1.f), c = rc_cos(lr,1.f);
      sm[0][i] = make_float2(v.x*s, v.y*s);
      lp[i] = make_float2(v.x*c, v.y*c);
    }
  }

  int cur = 0;
  if (!zrow){
    for (int ls=0; (1<<ls)<N; ++ls){
      const int Ns = 1<<ls;
      __syncthreads();
      for (int j=tid; j<N/2; j+=T){
        const int m = j & (Ns-1);
        const int base = ((j>>ls)<<(ls+1)) + m;
        float2 va = sm[cur][j];
        float2 vb = sm[cur][j + N/2];
        float ang = a.dirsign * (TWOPI_F * (float)m / (float)(2*Ns));
        float sn, cs;
        __sincosf(ang,&sn,&cs);
        float2 bw = make_float2(vb.x*cs - vb.y*sn, vb.x*sn + vb.y*cs);
        sm[cur^1][base]    = make_float2(va.x+bw.x, va.y+bw.y);
        sm[cur^1][base+Ns] = make_float2(va.x-bw.x, va.y-bw.y);
      }
      cur ^= 1;
    }
  }
  __syncthreads();

  const float sc = a.scale;
  if constexpr (POST==0){
    float2* dp = a.dst + (size_t)img*N*N + (size_t)row*N;
    for (int i=tid;i<N;i+=T){ float2 v=sm[cur][i]; dp[i]=make_float2(v.x*sc,v.y*sc); }
  } else if constexpr (POST==1){
    float a1=0.f,a2=0.f;
    for (int i=tid;i<N;i+=T){ float v=sm[cur][i].x*sc; a1+=fabsf(v); a2+=v*v; }
    float vals[2]={a1,a2};
    __shared__ float red[2*4];
    blockAccumN<2>(a.slots, vals, red);
  } else if constexpr (POST==2){
    float2* dp = a.dst + (size_t)img*N*N + (size_t)row*N;
    float am=0.f;
    for (int i=tid;i<N;i+=T){
      float2 v=sm[cur][i]; v.x*=sc; v.y*=sc; dp[i]=v;
      am += sqrtf(v.x*v.x+v.y*v.y);
    }
    float vals[1]={am};
    __shared__ float red1[4];
    blockAccumN<1>(a.slots + img, vals, red1);
  } else if constexpr (POST==3){
    float2* dp = a.dst + (size_t)img*N*N + (size_t)row*N;
    float s2=0.f,s3=0.f,s4=0.f;
    for (int i=tid;i<N;i+=T){
      float2 v=sm[cur][i]; v.x*=sc; v.y*=sc; dp[i]=v;
      float x=v.x, x2=x*x; s2+=x2; s3+=x2*x; s4+=x2*x2;
    }
    float vals[3]={s2,s3,s4};
    __shared__ float red3[3*4];
    blockAccumN<3>(a.slots, vals, red3);
  } else if constexpr (POST==4){
    const float2* B = a.aux;
    constexpr size_t N2 = (size_t)N*N;
    float acc[13];
    #pragma unroll
    for (int k=0;k<13;k++) acc[k]=0.f;
    for (int i=tid;i<N;i+=T){
      float2 p=sm[cur][i]; p.x*=sc; p.y*=sc;
      float m = sqrtf(p.x*p.x+p.y*p.y);
      float rp=0.f, ip=0.f;
      if (m>0.f){ rp=(p.y*p.y-p.x*p.x)/m; ip=2.f*p.x*p.y/m; }
      size_t pos = (size_t)row*N + i;
      acc[0]+=m;
      #pragma unroll
      for (int k=0;k<4;k++){
        float2 z = B[k*N2+pos];
        float mk = sqrtf(z.x*z.x+z.y*z.y);
        acc[1+k]+=mk*m; acc[5+k]+=z.x*rp; acc[9+k]+=z.x*ip;
      }
    }
    __shared__ float redp[13*4];
    blockAccumN<13>(a.slots + (size_t)img*13, acc, redp);
  }
}

// in-place batched square transpose (tile-pair swap)
__global__ void k_trip(float2* a, int n){
  int bi = blockIdx.x, bj = blockIdx.y;
  if (bj < bi) return;
  float2* img = a + (size_t)blockIdx.z*n*n;
  __shared__ float2 t0[32][33], t1[32][33];
  int r0=bi*32, c0=bj*32;
  for (int dy=threadIdx.y; dy<32; dy+=8){
    t0[dy][threadIdx.x] = img[(size_t)(r0+dy)*n + c0 + threadIdx.x];
    if (bi!=bj) t1[dy][threadIdx.x] = img[(size_t)(c0+dy)*n + r0 + threadIdx.x];
  }
  __syncthreads();
  for (int dy=threadIdx.y; dy<32; dy+=8){
    img[(size_t)(c0+dy)*n + r0 + threadIdx.x] = t0[threadIdx.x][dy];
    if (bi!=bj) img[(size_t)(r0+dy)*n + c0 + threadIdx.x] = t1[threadIdx.x][dy];
  }
}

// direct circular autocorrelation, 41 unique lags of the 9x9 window
// MODE 0: |z| of complex input; MODE 1: z.x
template<int MODE>
__global__ void k_ac(const float2* base, int n, int lgn, int imgStride, double* slots){
  __shared__ float t[72][73];
  const float2* img = base + (size_t)blockIdx.z * imgStride;
  const int ty0 = blockIdx.y*64, tx0 = blockIdx.x*64;
  for (int idx = threadIdx.x; idx < 72*72; idx += 256){
    int ly = idx/72, lx = idx-ly*72;
    int gy = (ty0 + ly - 4) & (n-1), gx = (tx0 + lx - 4) & (n-1);
    float2 v = img[((size_t)gy<<lgn) + gx];
    t[ly][lx] = MODE ? v.x : sqrtf(v.x*v.x+v.y*v.y);
  }
  __syncthreads();
  float acc[41];
  #pragma unroll
  for (int k=0;k<41;k++) acc[k]=0.f;
  for (int p = threadIdx.x; p < 4096; p += 256){
    int ly = (p>>6) + 4, lx = (p&63) + 4;
    float m0 = t[ly][lx];
    #pragma unroll
    for (int dj=1; dj<=4; dj++)
      #pragma unroll
      for (int di=-4; di<=4; di++)
        acc[(dj-1)*9 + di+4] += m0 * t[ly+di][lx+dj];
    #pragma unroll
    for (int di=0; di<=4; di++)
      acc[36+di] += m0 * t[ly+di][lx];
  }
  __shared__ float red[41*4];
  blockAccumN<41>(slots + (size_t)blockIdx.z*41, acc, red);
}

// ---------------- misc kernels ----------------------------------------------
__global__ void k_init(double* S, unsigned* SU, float* out, int nout){
  int i = blockIdx.x*blockDim.x + threadIdx.x;
  if (i < SL_TOT) S[i]=0.0;
  if (i==0){ SU[0]=0xFFFFFFFFu; SU[1]=0u; }
  if (i < nout) out[i]=0.f;
}
__global__ void k_imgstats1(const float* __restrict__ x, int n, double* S, unsigned* SU){
  int stride = gridDim.x*blockDim.x;
  float s=0.f, mn=3.4e38f, mx=-3.4e38f;
  for (int i=blockIdx.x*blockDim.x+threadIdx.x; i<n; i+=stride){
    float v=x[i]; s+=v; mn=fminf(mn,v); mx=fmaxf(mx,v);
  }
  waveAccum(S+0, s);
  for (int o=32;o>0;o>>=1){ mn=fminf(mn,__shfl_down(mn,o)); mx=fmaxf(mx,__shfl_down(mx,o)); }
  if ((threadIdx.x&63)==0){
    unsigned em=__float_as_uint(mn); em=(em>>31)? ~em : (em|0x80000000u);
    unsigned eM=__float_as_uint(mx); eM=(eM>>31)? ~eM : (eM|0x80000000u);
    atomicMin(SU+0, em); atomicMax(SU+1, eM);
  }
}
__global__ void k_imgstats2(const float* __restrict__ x, int n, double* S){
  float mean = (float)(S[0]/(double)n);
  int stride = gridDim.x*blockDim.x;
  float s2=0,s3=0,s4=0;
  for (int i=blockIdx.x*blockDim.x+threadIdx.x; i<n; i+=stride){
    float d=x[i]-mean, d2=d*d; s2+=d2; s3+=d2*d; s4+=d2*d2;
  }
  waveAccum(S+1,s2); waveAccum(S+2,s3); waveAccum(S+3,s4);
}
__global__ void k_croplo(const float2* __restrict__ src, float2* dst, int nn, int lgn){
  int idx = blockIdx.x*blockDim.x+threadIdx.x;
  int i = idx>>lgn, j = idx&(nn-1);
  int h = nn>>1;
  int si = (i<h)?i:i+nn;
  int sj = (j<h)?j:j+nn;
  float lom = rc_cos(lograd(i,j,nn),1.f);
  float2 v = src[(size_t)si*(2*nn)+sj];
  dst[idx] = make_float2(v.x*lom, v.y*lom);
}
__global__ void k_gram(const float2* __restrict__ B, int n2, double* slots){
  float p[20];
  #pragma unroll
  for (int i=0;i<20;i++) p[i]=0.f;
  int stride = gridDim.x*blockDim.x;
  for (int i=blockIdx.x*blockDim.x+threadIdx.x; i<n2; i+=stride){
    float2 z0=B[i], z1=B[i+(size_t)n2], z2=B[i+2*(size_t)n2], z3=B[i+3*(size_t)n2];
    float m0=sqrtf(z0.x*z0.x+z0.y*z0.y), m1=sqrtf(z1.x*z1.x+z1.y*z1.y);
    float m2=sqrtf(z2.x*z2.x+z2.y*z2.y), m3=sqrtf(z3.x*z3.x+z3.y*z3.y);
    float r0=z0.x, r1=z1.x, r2=z2.x, r3=z3.x;
    p[0]+=m0*m0; p[1]+=m0*m1; p[2]+=m0*m2; p[3]+=m0*m3;
    p[4]+=m1*m1; p[5]+=m1*m2; p[6]+=m1*m3;
    p[7]+=m2*m2; p[8]+=m2*m3; p[9]+=m3*m3;
    p[10]+=r0*r0; p[11]+=r0*r1; p[12]+=r0*r2; p[13]+=r0*r3;
    p[14]+=r1*r1; p[15]+=r1*r2; p[16]+=r1*r3;
    p[17]+=r2*r2; p[18]+=r2*r3; p[19]+=r3*r3;
  }
  __shared__ float red[20*4];
  blockAccumN<20>(slots,p,red);
}
__global__ void k_crx3(const float2* __restrict__ RP, const float2* __restrict__ B3, double* S){
  float a[35];
  #pragma unroll
  for (int i=0;i<35;i++) a[i]=0.f;
  int stride = gridDim.x*blockDim.x;
  for (int idx=blockIdx.x*blockDim.x+threadIdx.x; idx<16384; idx+=stride){
    int u=idx>>7, v=idx&127;
    float P0=RP[idx].x;
    float P1=RP[(u<<7) | ((v-1)&127)].x;
    float P2=RP[(u<<7) | ((v+1)&127)].x;
    float P3=RP[(((u-1)&127)<<7) | v].x;
    float P4=RP[(((u+1)&127)<<7) | v].x;
    float P[5]={P0,P1,P2,P3,P4};
    float R[4];
    #pragma unroll
    for (int b=0;b<4;b++) R[b]=B3[b*16384 + (v<<7) + u].x;   // transposed pairing
    #pragma unroll
    for (int i=0;i<4;i++)
      #pragma unroll
      for (int j=0;j<5;j++) a[i*5+j]+=R[i]*P[j];
    int k=20;
    #pragma unroll
    for (int i=0;i<5;i++)
      #pragma unroll
      for (int j=i;j<5;j++){ a[k]+=P[i]*P[j]; k++; }
  }
  __shared__ float red[35*4];
  float lo[20], hi[15];
  #pragma unroll
  for (int k=0;k<20;k++) lo[k]=a[k];
  #pragma unroll
  for (int k=0;k<15;k++) hi[k]=a[20+k];
  blockAccumN<20>(S+280, lo, red);
  blockAccumN<15>(S+300, hi, red);
}
__global__ void k_lowstats(const float2* __restrict__ lp, double* S){
  __shared__ float red[4];
  __shared__ float smu;
  int lane=threadIdx.x&63, wid=threadIdx.x>>6;
  float s=0.f;
  for (int i=threadIdx.x;i<4096;i+=256) s+=lp[i].x;
  for (int o=32;o>0;o>>=1) s+=__shfl_down(s,o);
  if (lane==0) red[wid]=s;
  __syncthreads();
  if (threadIdx.x==0){
    float t=red[0]+red[1]+red[2]+red[3];
    S[22]=(double)t; smu=t/4096.f;
  }
  __syncthreads();
  float mu=smu, ad=0.f;
  for (int i=threadIdx.x;i<4096;i+=256) ad+=fabsf(lp[i].x-mu);
  for (int o=32;o>0;o>>=1) ad+=__shfl_down(ad,o);
  if (lane==0) red[wid]=ad;
  __syncthreads();
  if (threadIdx.x==0) S[23]=(double)(red[0]+red[1]+red[2]+red[3]);
}
__global__ void k_imlpstats(const float2* __restrict__ ip, double* Smom, double* Sac){
  __shared__ float t[64][65];
  for (int i=threadIdx.x;i<4096;i+=256) t[i>>6][i&63]=ip[i].x;
  __syncthreads();
  float s2=0.f,s3=0.f,s4=0.f;
  float acc[41];
  #pragma unroll
  for (int k=0;k<41;k++) acc[k]=0.f;
  for (int p=threadIdx.x;p<4096;p+=256){
    int y=p>>6, x=p&63;
    float m0=t[y][x], m02=m0*m0;
    s2+=m02; s3+=m02*m0; s4+=m02*m02;
    #pragma unroll
    for (int dj=1;dj<=4;dj++)
      #pragma unroll
      for (int di=-4;di<=4;di++)
        acc[(dj-1)*9+di+4] += m0 * t[(y+di)&63][(x+dj)&63];
    #pragma unroll
    for (int di=0;di<=4;di++)
      acc[36+di] += m0 * t[(y+di)&63][x];
  }
  __shared__ float red[41*4];
  float mom[3]={s2,s3,s4};
  blockAccumN<3>(Smom, mom, red);
  blockAccumN<41>(Sac, acc, red);
}

__global__ void k_final(const double* __restrict__ S, const unsigned* __restrict__ SU, float* out){
  const int tid = threadIdx.x;
  const double N0 = 1048576.0;
  const double npix[4]={1048576.0,262144.0,65536.0,16384.0};
  for (int e=tid; e<81*16; e+=256){
    int w=e>>4, s=(e>>2)&3, b=e&3;
    int i=w/9, j=w-i*9;
    int k=lagIdx(i-4,j-4);
    double n2=npix[s];
    double mu=S[6+s*4+b]/n2;
    out[24+(w*4+s)*4+b]=(float)(S[SL_ACE+(s*4+b)*41+k]/n2 - mu*mu);
  }
  for (int e=tid; e<81*4; e+=256){
    int w=e>>2, s=e&3;
    int i=w/9, j=w-i*9;
    int k=lagIdx(i-4,j-4);
    out[1330+w*5+s]=(float)(S[SL_ACR+s*41+k]/(2.0*npix[s]));
  }
  for (int w=tid; w<81; w+=256){
    int i=w/9, j=w-i*9;
    int k=lagIdx(i-4,j-4);
    out[1330+w*5+4]=(float)(S[SL_ALP+k]/4096.0);
  }
  if (tid==0){
    double mean0=S[0]/N0, var0=S[1]/(N0-1.0);
    out[0]=(float)mean0; out[1]=(float)var0;
    out[2]=(float)((S[2]/N0)/(var0*sqrt(var0)));
    out[3]=(float)((S[3]/N0)/(var0*var0));
    unsigned em=SU[0], eM=SU[1];
    em=(em&0x80000000u)?(em&0x7FFFFFFFu):~em;
    eM=(eM&0x80000000u)?(eM&0x7FFFFFFFu):~eM;
    out[4]=__uint_as_float(em); out[5]=__uint_as_float(eM);
    out[6]=(float)(S[4]/N0);
    for (int s=0;s<4;s++) for (int b=0;b<4;b++) out[7+s*4+b]=(float)(S[6+s*4+b]/npix[s]);
    out[23]=(float)(S[23]/4096.0);
    for (int s=0;s<4;s++){
      double n2=npix[s];
      double vari=S[24+s*3]/(2.0*n2);
      int ok=(vari/var0>1e-6);
      out[1320+s]= ok? (float)(0.5*(S[25+s*3]/n2)/(vari*sqrt(vari))) : 0.f;
      out[1325+s]= ok? (float)(0.5*(S[26+s*3]/n2)/(vari*vari)) : 3.f;
    }
    { double vari=S[36]/4096.0; int ok=(vari/var0>1e-6);
      out[1324]= ok? (float)((S[37]/4096.0)/(vari*sqrt(vari))) : 0.f;
      out[1329]= ok? (float)((S[38]/4096.0)/(vari*vari)) : 3.f; }
    for (int s=0;s<4;s++){
      double n2=npix[s];
      const double* G=S+40+s*20;
      for (int i=0;i<4;i++) for (int j=0;j<4;j++){
        int a2=i<j?i:j, bb=i<j?j:i;
        int p=a2*(7-a2)/2+bb;
        double Si=S[6+s*4+i], Sj=S[6+s*4+j];
        out[1735+(i*4+j)*5+s]=(float)((G[p]-Si*Sj/n2)/n2);
        out[1879+(i*8+j)*5+s]=(float)(G[10+p]/n2);
      }
    }
    for (int s=0;s<3;s++){
      double n2=npix[s];
      for (int j=0;j<4;j++){
        const double* P=S+120+(s*4+j)*13;
        double Smj=P[0];
        for (int i=0;i<4;i++){
          double Si=S[6+s*4+i];
          out[1815+(i*4+j)*4+s]=(float)((P[1+i]-Si*Smj/n2)/n2);
          out[2199+(i*8+j)*4+s]=(float)(P[5+i]/n2);
          out[2199+(i*8+(j+4))*4+s]=(float)(P[9+i]/n2);
        }
      }
    }
    for (int i=0;i<4;i++) for (int j=0;j<5;j++)
      out[2199+(i*8+j)*4+3]=(float)(S[280+i*5+j]/16384.0);
    for (int i=0;i<5;i++) for (int j=0;j<5;j++){
      int a2=i<j?i:j, bb=i<j?j:i;
      int p=a2*(9-a2)/2+bb;
      out[1879+(i*8+j)*5+4]=(float)(S[300+p]/4096.0);
    }
    out[2455]=(float)(S[5]/N0);
  }
}

// ---------------- host orchestration -----------------------------------------
template<int PRE,int POST>
static void lfft(int n, int nimg, FArgs a, hipStream_t st){
  switch(n){
    case 1024: k_fft<1024,PRE,POST><<<dim3(1024,nimg),fftT(1024),0,st>>>(a); break;
    case 512:  k_fft<512 ,PRE,POST><<<dim3(512 ,nimg),fftT(512 ),0,st>>>(a); break;
    case 256:  k_fft<256 ,PRE,POST><<<dim3(256 ,nimg),fftT(256 ),0,st>>>(a); break;
    case 128:  k_fft<128 ,PRE,POST><<<dim3(128 ,nimg),fftT(128 ),0,st>>>(a); break;
    case 64:   k_fft<64  ,PRE,POST><<<dim3(64  ,nimg),fftT(64  ),0,st>>>(a); break;
  }
}

extern "C" void kernel_launch(void* const* d_in, const int* in_sizes, int n_in,
                              void* d_out, int out_size, void* d_ws, size_t ws_size,
                              hipStream_t stream){
  const float* im = (const float*)d_in[0];
  float* out = (float*)d_out;
  char* w = (char*)d_ws;
  float2* CA4 = (float2*)w;                              // 32 MB: 4 bands
  float2* CB4 = (float2*)(w + ((size_t)32<<20));         // 16 MB: scratch
  float2* CC  = (float2*)(w + ((size_t)48<<20));         // 8 MB: unor / tails
  size_t off = (size_t)56<<20;
  float2* LOD[5]; int lsz[5]={1024,512,256,128,64};
  for (int i=0;i<5;i++){ LOD[i]=(float2*)(w+off); off += (size_t)lsz[i]*lsz[i]*8; }
  off = (off + 255) & ~(size_t)255;
  double* S = (double*)(w+off);
  unsigned* SU = (unsigned*)(w+off+SL_TOT*8);

  k_init<<<10,256,0,stream>>>(S,SU,out,2456);
  k_imgstats1<<<512,256,0,stream>>>(im,1048576,S,SU);
  k_imgstats2<<<512,256,0,stream>>>(im,1048576,S);

  FArgs a{};
  // forward fft2 (3 passes) -> F^T in CA4
  a = FArgs{}; a.rsrc=im; a.dst=CA4; a.dirsign=-1.f; a.scale=1.f;
  lfft<1,0>(1024,1,a,stream);
  k_trip<<<dim3(32,32,1),dim3(32,8),0,stream>>>(CA4,1024);
  a = FArgs{}; a.src=CA4; a.dst=CA4; a.dirsign=-1.f; a.scale=1.f;
  lfft<0,0>(1024,1,a,stream);
  // split (lo0 -> LOD[0], hi -> chain) + hi0 ifft2 + |.|,^2 sums
  a = FArgs{}; a.src=CA4; a.dst=CB4; a.aux2=LOD[0]; a.dirsign=1.f; a.scale=1.f/1024.f;
  lfft<9,0>(1024,1,a,stream);
  k_trip<<<dim3(32,32,1),dim3(32,8),0,stream>>>(CB4,1024);
  a = FArgs{}; a.src=CB4; a.dst=CB4; a.slots=S+4; a.dirsign=1.f; a.scale=1.f/1024.f;
  lfft<0,1>(1024,1,a,stream);

  for (int s=0;s<4;s++){
    const int n=1024>>s, nt=n/32, n2=n*n, lg=10-s;
    const float inv = 1.f/(float)n;
    // bands (batched over 4)
    a = FArgs{}; a.src=LOD[s]; a.dst=CA4; a.b0=0; a.dirsign=1.f; a.scale=inv;
    lfft<2,0>(n,4,a,stream);
    k_trip<<<dim3(nt,nt,4),dim3(32,8),0,stream>>>(CA4,n);
    a = FArgs{}; a.src=CA4; a.dst=CA4; a.slots=S+6+s*4; a.dirsign=1.f; a.scale=inv;
    lfft<0,2>(n,4,a,stream);
    k_gram<<<256,256,0,stream>>>(CA4,n2,S+40+s*20);
    k_ac<0><<<dim3(n/64,n/64,4),256,0,stream>>>(CA4,n,lg,n2,S+SL_ACE+(size_t)(s*4)*41);
    // unor
    a = FArgs{}; a.src=LOD[s]; a.dst=CC; a.dirsign=1.f; a.scale=inv;
    lfft<3,0>(n,1,a,stream);
    k_trip<<<dim3(nt,nt,1),dim3(32,8),0,stream>>>(CC,n);
    a = FArgs{}; a.src=CC; a.dst=CC; a.slots=S+24+s*3; a.dirsign=1.f; a.scale=inv;
    lfft<0,3>(n,1,a,stream);
    k_ac<1><<<dim3(n/64,n/64,1),256,0,stream>>>(CC,n,lg,n2,S+SL_ACR+(size_t)s*41);
    // next lodft
    int nn=n>>1;
    k_croplo<<<dim3(nn*nn/256),256,0,stream>>>(LOD[s],LOD[s+1],nn,lg-1);
    if (s<3){
      const int nb = (s==0)? 2 : 4;
      for (int b0=0;b0<4;b0+=nb){
        a = FArgs{}; a.src=LOD[s+1]; a.dst=CB4; a.b0=b0; a.dirsign=1.f; a.scale=inv;
        lfft<4,0>(n,nb,a,stream);
        k_trip<<<dim3(nt,nt,nb),dim3(32,8),0,stream>>>(CB4,n);
        a = FArgs{}; a.src=CB4; a.dst=CB4; a.aux=CA4;
        a.slots=S+120+(size_t)(s*4+b0)*13; a.dirsign=1.f; a.scale=inv;
        lfft<0,4>(n,nb,a,stream);
      }
    } else {
      float2* LPB=CC; float2* IMB=CC+4096; float2* RPB=CC+8192;
      // lowpass
      a = FArgs{}; a.src=LOD[4]; a.dst=LPB; a.dirsign=1.f; a.scale=1.f/64.f;
      lfft<0,0>(64,1,a,stream);
      k_trip<<<dim3(2,2,1),dim3(32,8),0,stream>>>(LPB,64);
      a = FArgs{}; a.src=LPB; a.dst=LPB; a.dirsign=1.f; a.scale=1.f/64.f;
      lfft<0,0>(64,1,a,stream);
      k_lowstats<<<1,256,0,stream>>>(LPB,S);
      // imlp
      a = FArgs{}; a.src=LOD[4]; a.dst=IMB; a.dirsign=1.f; a.scale=1.f/64.f;
      lfft<7,0>(64,1,a,stream);
      k_trip<<<dim3(2,2,1),dim3(32,8),0,stream>>>(IMB,64);
      a = FArgs{}; a.src=IMB; a.dst=IMB; a.dirsign=1.f; a.scale=1.f/64.f;
      lfft<0,0>(64,1,a,stream);
      k_imlpstats<<<1,256,0,stream>>>(IMB,S+36,S+SL_ALP);
      // rparents (expanded lowpass) + crx3
      a = FArgs{}; a.src=LOD[4]; a.dst=RPB; a.dirsign=1.f; a.scale=1.f/128.f;
      lfft<5,0>(128,1,a,stream);
      k_trip<<<dim3(4,4,1),dim3(32,8),0,stream>>>(RPB,128);
      a = FArgs{}; a.src=RPB; a.dst=RPB; a.dirsign=1.f; a.scale=1.f/128.f;
      lfft<0,0>(128,1,a,stream);
      k_crx3<<<64,256,0,stream>>>(RPB,CA4,S);
    }
  }
  k_final<<<1,256,0,stream>>>(S,SU,out);
  (void)in_sizes; (void)n_in; (void)out_size; (void)ws_size;
}

// Round 3
// 711.516 us; speedup vs baseline: 7.3720x; 1.3386x over previous
//
#include <hip/hip_runtime.h>

#define PI_F     3.14159265358979323846f
#define TWOPI_F  6.28318530717958647692f
#define HPI_F    1.57079632679489661923f

constexpr int fftT(int N){ return N>=512 ? 256 : (N/2 < 64 ? 64 : N/2); }

// S-slot layout (doubles), replicated REP times (replica stride SL_TOT)
#define SL_ACE 340          // 16 x 41
#define SL_ACR 996          // 4 x 41
#define SL_ALP 1160         // 41
#define SL_TOT 1280
#define REP 8

__device__ __forceinline__ float fcoord(int k, int n){
  int s = k ^ (n>>1);
  return (float)(s - (n>>1)) / (float)(n>>1);
}
__device__ __forceinline__ float lograd(int kr, int kc, int n){
  if (kr==0 && kc==0) return log2f(2.0f/(float)n);
  float x = fcoord(kc,n), y = fcoord(kr,n);
  return 0.5f*log2f(x*x+y*y);
}
__device__ __forceinline__ float rc_sin(float lr, float shift){
  float t = fminf(fmaxf(lr+shift,0.f),1.f); return __sinf(HPI_F*t);
}
__device__ __forceinline__ float rc_cos(float lr, float shift){
  float t = fminf(fmaxf(lr+shift,0.f),1.f); return __cosf(HPI_F*t);
}
__device__ __forceinline__ float bandmask(int kr, int kc, int n, int b){
  float x = fcoord(kc,n), y = fcoord(kr,n);
  float ang = atan2f(y,x);
  float lr = lograd(kr,kc,n);
  float him = rc_sin(lr,2.0f);
  float th = ang - 0.25f*PI_F*(float)b;
  float u = th + PI_F;
  u -= TWOPI_F*floorf(u*(1.0f/TWOPI_F));
  float thw = u - PI_F;
  float c = __cosf(th);
  float am = (fabsf(thw) < HPI_F) ? (1.7888543819998317f*c*c*c) : 0.0f;
  return am*him;
}
__device__ __forceinline__ int lagIdx(int di, int dj){
  if (dj < 0 || (dj==0 && di<0)){ di=-di; dj=-dj; }
  return dj==0 ? 36+di : (dj-1)*9 + (di+4);
}

__device__ __forceinline__ void atomAddD(double* p, double v){
  unsafeAtomicAdd(p, v);   // native global_atomic_add_f64 on gfx950
}
// block-level multi-slot reduce, then ONE native-f64 atomic per slot per block,
// spread over REP replica arrays (replica stride = SL_TOT doubles)
template<int NS>
__device__ __forceinline__ void blockAccumN(double* base, const float* vals, float* red){
  const int lane = threadIdx.x & 63, wid = threadIdx.x >> 6;
  const int nw = (int)(blockDim.x >> 6);
  #pragma unroll
  for (int k=0;k<NS;k++){
    float v = vals[k];
    #pragma unroll
    for (int o=32;o>0;o>>=1) v += __shfl_down(v,o);
    if (lane==0) red[k*nw+wid]=v;
  }
  __syncthreads();
  const int rep = (int)((blockIdx.x ^ (blockIdx.y<<1) ^ (blockIdx.z<<2)) & 7) * SL_TOT;
  if ((int)threadIdx.x < NS){
    float s=0.f;
    for (int w2=0;w2<nw;w2++) s += red[(int)threadIdx.x*nw+w2];
    atomAddD(base+rep+(int)threadIdx.x,(double)s);
  }
  __syncthreads();
}

// ---------------- fused FFT kernel ------------------------------------------
// PRE: 0 cplx row, 1 real row, 2 bandmask from LOD^T, 3 him mask, 4 padband,
//      5 padlp, 7 imlp mask, 9 split (hi to LDS, lo0 to aux2)
// POST: 0 store, 1 sum|x|,x^2, 2 store+sum mag, 3 store+moments, 4 parentred
struct FArgs {
  const float2* src; float2* dst;
  const float* rsrc;
  const float2* aux;
  float2* aux2;
  double* slots;
  float dirsign, scale;
  int b0;
};

#define TWI(k) ((k)+((k)>>4))

template<int N, int PRE, int POST>
__global__ __launch_bounds__(fftT(N)) void k_fft(FArgs a){
  constexpr int T = fftT(N);
  constexpr int LG = (N==1024)?10:(N==512)?9:(N==256)?8:(N==128)?7:6;
  __shared__ float2 sm[2][N];
  __shared__ float2 tw[N/2 + N/32];
  const int row = blockIdx.x;
  const int img = blockIdx.y;
  const int tid = threadIdx.x;
  bool zrow = false;

  for (int k=tid;k<N/2;k+=T){
    float sn, cs;
    __sincosf(TWOPI_F*(float)k/(float)N, &sn, &cs);
    tw[TWI(k)] = make_float2(cs, sn);        // exp(+i 2pi k/N); sign applied below
  }

  if constexpr (PRE==1){
    const float* rp = a.rsrc + (size_t)row*N;
    for (int i=tid;i<N;i+=T) sm[0][i] = make_float2(rp[i],0.f);
  } else if constexpr (PRE==0){
    const float2* sp = a.src + (size_t)img*N*N + (size_t)row*N;
    for (int i=tid;i<N;i+=T) sm[0][i] = sp[i];
  } else if constexpr (PRE==2){           // LOD^T storage: (row,i) = orig (kr=i,kc=row)
    const float2* sp = a.src + (size_t)row*N;
    const int b = a.b0 + img;
    for (int i=tid;i<N;i+=T){
      float2 v = sp[i];
      float m = bandmask(i, row, N, b);
      sm[0][i] = make_float2(-v.y*m, v.x*m);  // (-1j)^3 = +i
    }
  } else if constexpr (PRE==3){
    const float2* sp = a.src + (size_t)row*N;
    for (int i=tid;i<N;i+=T){
      float2 v = sp[i];
      float him = rc_sin(lograd(i,row,N),2.f);
      sm[0][i] = make_float2(v.x*him, v.y*him);
    }
  } else if constexpr (PRE==4 || PRE==5){ // pad from LOD^T of size N/2
    constexpr int M = N/2, Q = N/4;
    const int fi = (row<Q)? row : (row>=N-Q ? row-M : -1);
    if (fi < 0){
      for (int i=tid;i<N;i+=T) sm[0][i]=make_float2(0.f,0.f);
      zrow = true;
    } else {
      const float2* sp = a.src + (size_t)fi*M;
      const int b = a.b0 + img;
      for (int i=tid;i<N;i+=T){
        int fj = (i<Q)? i : (i>=N-Q ? i-M : -1);
        float2 r = make_float2(0.f,0.f);
        if (fj>=0){
          float2 v = sp[fj];
          if constexpr (PRE==4){
            float m = bandmask(fj, fi, M, b);
            r = make_float2(-v.y*m, v.x*m);
          } else {
            if (!(fi==0 && fj==0)) r = v;
          }
        }
        sm[0][i] = r;
      }
    }
  } else if constexpr (PRE==7){
    const float2* sp = a.src + (size_t)row*N;
    for (int i=tid;i<N;i+=T){
      float2 v = sp[i];
      if (row==0 && i==0) v = make_float2(0.f,0.f);
      float lo = rc_cos(lograd(i,row,N),1.f);
      sm[0][i] = make_float2(v.x*lo, v.y*lo);
    }
  } else if constexpr (PRE==9){
    const float2* sp = a.src + (size_t)row*N;
    float2* lp = a.aux2 + (size_t)row*N;
    for (int i=tid;i<N;i+=T){
      float2 v = sp[i];
      float lr = lograd(i,row,N);
      float s = rc_sin(lr,1.f), c = rc_cos(lr,1.f);
      sm[0][i] = make_float2(v.x*s, v.y*s);
      lp[i] = make_float2(v.x*c, v.y*c);
    }
  }

  int cur = 0;
  if (!zrow){
    const float ds = a.dirsign;
    for (int ls=0; ls<LG; ++ls){
      const int Ns = 1<<ls;
      const int sh = LG-1-ls;
      __syncthreads();
      for (int j=tid; j<N/2; j+=T){
        const int m = j & (Ns-1);
        const int base = ((j>>ls)<<(ls+1)) + m;
        float2 va = sm[cur][j];
        float2 vb = sm[cur][j + N/2];
        float2 w = tw[TWI(m<<sh)];
        float wy = ds*w.y;
        float2 bw = make_float2(vb.x*w.x - vb.y*wy, vb.x*wy + vb.y*w.x);
        sm[cur^1][base]    = make_float2(va.x+bw.x, va.y+bw.y);
        sm[cur^1][base+Ns] = make_float2(va.x-bw.x, va.y-bw.y);
      }
      cur ^= 1;
    }
  }
  __syncthreads();

  const float sc = a.scale;
  if constexpr (POST==0){
    float2* dp = a.dst + (size_t)img*N*N + (size_t)row*N;
    for (int i=tid;i<N;i+=T){ float2 v=sm[cur][i]; dp[i]=make_float2(v.x*sc,v.y*sc); }
  } else if constexpr (POST==1){
    float a1=0.f,a2=0.f;
    for (int i=tid;i<N;i+=T){ float v=sm[cur][i].x*sc; a1+=fabsf(v); a2+=v*v; }
    float vals[2]={a1,a2};
    __shared__ float red[2*4];
    blockAccumN<2>(a.slots, vals, red);
  } else if constexpr (POST==2){
    float2* dp = a.dst + (size_t)img*N*N + (size_t)row*N;
    float am=0.f;
    for (int i=tid;i<N;i+=T){
      float2 v=sm[cur][i]; v.x*=sc; v.y*=sc; dp[i]=v;
      am += sqrtf(v.x*v.x+v.y*v.y);
    }
    float vals[1]={am};
    __shared__ float red1[4];
    blockAccumN<1>(a.slots + img, vals, red1);
  } else if constexpr (POST==3){
    float2* dp = a.dst + (size_t)img*N*N + (size_t)row*N;
    float s2=0.f,s3=0.f,s4=0.f;
    for (int i=tid;i<N;i+=T){
      float2 v=sm[cur][i]; v.x*=sc; v.y*=sc; dp[i]=v;
      float x=v.x, x2=x*x; s2+=x2; s3+=x2*x; s4+=x2*x2;
    }
    float vals[3]={s2,s3,s4};
    __shared__ float red3[3*4];
    blockAccumN<3>(a.slots, vals, red3);
  } else if constexpr (POST==4){
    const float2* B = a.aux;
    constexpr size_t N2 = (size_t)N*N;
    float acc[13];
    #pragma unroll
    for (int k=0;k<13;k++) acc[k]=0.f;
    for (int i=tid;i<N;i+=T){
      float2 p=sm[cur][i]; p.x*=sc; p.y*=sc;
      float m = sqrtf(p.x*p.x+p.y*p.y);
      float rp=0.f, ip=0.f;
      if (m>0.f){ rp=(p.y*p.y-p.x*p.x)/m; ip=2.f*p.x*p.y/m; }
      size_t pos = (size_t)row*N + i;
      acc[0]+=m;
      #pragma unroll
      for (int k=0;k<4;k++){
        float2 z = B[k*N2+pos];
        float mk = sqrtf(z.x*z.x+z.y*z.y);
        acc[1+k]+=mk*m; acc[5+k]+=z.x*rp; acc[9+k]+=z.x*ip;
      }
    }
    __shared__ float redp[13*4];
    blockAccumN<13>(a.slots + (size_t)img*13, acc, redp);
  }
}

// in-place batched square transpose (tile-pair swap)
__global__ void k_trip(float2* a, int n){
  int bi = blockIdx.x, bj = blockIdx.y;
  if (bj < bi) return;
  float2* img = a + (size_t)blockIdx.z*n*n;
  __shared__ float2 t0[32][33], t1[32][33];
  int r0=bi*32, c0=bj*32;
  for (int dy=threadIdx.y; dy<32; dy+=8){
    t0[dy][threadIdx.x] = img[(size_t)(r0+dy)*n + c0 + threadIdx.x];
    if (bi!=bj) t1[dy][threadIdx.x] = img[(size_t)(c0+dy)*n + r0 + threadIdx.x];
  }
  __syncthreads();
  for (int dy=threadIdx.y; dy<32; dy+=8){
    img[(size_t)(c0+dy)*n + r0 + threadIdx.x] = t0[threadIdx.x][dy];
    if (bi!=bj) img[(size_t)(r0+dy)*n + c0 + threadIdx.x] = t1[threadIdx.x][dy];
  }
}

// direct circular autocorrelation, 41 unique lags of the 9x9 window
template<int MODE>
__global__ void k_ac(const float2* base, int n, int lgn, int imgStride, double* slots){
  __shared__ float t[72][73];
  const float2* img = base + (size_t)blockIdx.z * imgStride;
  const int ty0 = blockIdx.y*64, tx0 = blockIdx.x*64;
  for (int idx = threadIdx.x; idx < 72*72; idx += 256){
    int ly = idx/72, lx = idx-ly*72;
    int gy = (ty0 + ly - 4) & (n-1), gx = (tx0 + lx - 4) & (n-1);
    float2 v = img[((size_t)gy<<lgn) + gx];
    t[ly][lx] = MODE ? v.x : sqrtf(v.x*v.x+v.y*v.y);
  }
  __syncthreads();
  float acc[41];
  #pragma unroll
  for (int k=0;k<41;k++) acc[k]=0.f;
  for (int p = threadIdx.x; p < 4096; p += 256){
    int ly = (p>>6) + 4, lx = (p&63) + 4;
    float m0 = t[ly][lx];
    #pragma unroll
    for (int dj=1; dj<=4; dj++)
      #pragma unroll
      for (int di=-4; di<=4; di++)
        acc[(dj-1)*9 + di+4] += m0 * t[ly+di][lx+dj];
    #pragma unroll
    for (int di=0; di<=4; di++)
      acc[36+di] += m0 * t[ly+di][lx];
  }
  __shared__ float red[41*4];
  blockAccumN<41>(slots + (size_t)blockIdx.z*41, acc, red);
}

// ---------------- misc kernels ----------------------------------------------
__global__ void k_init(double* S, float* out, int nout){
  int i = blockIdx.x*blockDim.x + threadIdx.x;
  if (i < REP*SL_TOT) S[i]=0.0;
  if (i < nout) out[i]=0.f;
}
// raw moments + min/max, per-block partials (no atomics): PB[block][8]
__global__ __launch_bounds__(256) void k_imgstats(const float4* __restrict__ x, float* PB){
  float s1=0.f,s2=0.f,s3=0.f,s4=0.f, mn=3.4e38f, mx=-3.4e38f;
  const int base = blockIdx.x*1024 + threadIdx.x;
  #pragma unroll
  for (int it=0; it<4; ++it){
    float4 v = x[base + it*256];
    float vs[4]={v.x,v.y,v.z,v.w};
    #pragma unroll
    for (int k=0;k<4;k++){
      float t=vs[k], t2=t*t;
      s1+=t; s2+=t2; s3+=t2*t; s4+=t2*t2;
      mn=fminf(mn,t); mx=fmaxf(mx,t);
    }
  }
  __shared__ float wr[6][4];
  int lane=threadIdx.x&63, wid=threadIdx.x>>6;
  float sums[4]={s1,s2,s3,s4};
  #pragma unroll
  for (int k=0;k<4;k++){
    float v=sums[k];
    for (int o=32;o>0;o>>=1) v+=__shfl_down(v,o);
    if (lane==0) wr[k][wid]=v;
  }
  { float v=mn; for (int o=32;o>0;o>>=1) v=fminf(v,__shfl_down(v,o)); if(lane==0) wr[4][wid]=v; }
  { float v=mx; for (int o=32;o>0;o>>=1) v=fmaxf(v,__shfl_down(v,o)); if(lane==0) wr[5][wid]=v; }
  __syncthreads();
  if (threadIdx.x<4)  PB[blockIdx.x*8+threadIdx.x] = wr[threadIdx.x][0]+wr[threadIdx.x][1]+wr[threadIdx.x][2]+wr[threadIdx.x][3];
  if (threadIdx.x==4) PB[blockIdx.x*8+4] = fminf(fminf(wr[4][0],wr[4][1]),fminf(wr[4][2],wr[4][3]));
  if (threadIdx.x==5) PB[blockIdx.x*8+5] = fmaxf(fmaxf(wr[5][0],wr[5][1]),fmaxf(wr[5][2],wr[5][3]));
}
__global__ void k_croplo(const float2* __restrict__ src, float2* dst, int nn, int lgn){
  int idx = blockIdx.x*blockDim.x+threadIdx.x;
  int i = idx>>lgn, j = idx&(nn-1);
  int h = nn>>1;
  int si = (i<h)?i:i+nn;
  int sj = (j<h)?j:j+nn;
  float lom = rc_cos(lograd(i,j,nn),1.f);
  float2 v = src[(size_t)si*(2*nn)+sj];
  dst[idx] = make_float2(v.x*lom, v.y*lom);
}
__global__ void k_gram(const float2* __restrict__ B, int n2, double* slots){
  float p[20];
  #pragma unroll
  for (int i=0;i<20;i++) p[i]=0.f;
  int stride = gridDim.x*blockDim.x;
  for (int i=blockIdx.x*blockDim.x+threadIdx.x; i<n2; i+=stride){
    float2 z0=B[i], z1=B[i+(size_t)n2], z2=B[i+2*(size_t)n2], z3=B[i+3*(size_t)n2];
    float m0=sqrtf(z0.x*z0.x+z0.y*z0.y), m1=sqrtf(z1.x*z1.x+z1.y*z1.y);
    float m2=sqrtf(z2.x*z2.x+z2.y*z2.y), m3=sqrtf(z3.x*z3.x+z3.y*z3.y);
    float r0=z0.x, r1=z1.x, r2=z2.x, r3=z3.x;
    p[0]+=m0*m0; p[1]+=m0*m1; p[2]+=m0*m2; p[3]+=m0*m3;
    p[4]+=m1*m1; p[5]+=m1*m2; p[6]+=m1*m3;
    p[7]+=m2*m2; p[8]+=m2*m3; p[9]+=m3*m3;
    p[10]+=r0*r0; p[11]+=r0*r1; p[12]+=r0*r2; p[13]+=r0*r3;
    p[14]+=r1*r1; p[15]+=r1*r2; p[16]+=r1*r3;
    p[17]+=r2*r2; p[18]+=r2*r3; p[19]+=r3*r3;
  }
  __shared__ float red[20*4];
  blockAccumN<20>(slots,p,red);
}
__global__ void k_crx3(const float2* __restrict__ RP, const float2* __restrict__ B3, double* S){
  float a[35];
  #pragma unroll
  for (int i=0;i<35;i++) a[i]=0.f;
  int stride = gridDim.x*blockDim.x;
  for (int idx=blockIdx.x*blockDim.x+threadIdx.x; idx<16384; idx+=stride){
    int u=idx>>7, v=idx&127;
    float P0=RP[idx].x;
    float P1=RP[(u<<7) | ((v-1)&127)].x;
    float P2=RP[(u<<7) | ((v+1)&127)].x;
    float P3=RP[(((u-1)&127)<<7) | v].x;
    float P4=RP[(((u+1)&127)<<7) | v].x;
    float P[5]={P0,P1,P2,P3,P4};
    float R[4];
    #pragma unroll
    for (int b=0;b<4;b++) R[b]=B3[b*16384 + (v<<7) + u].x;
    #pragma unroll
    for (int i=0;i<4;i++)
      #pragma unroll
      for (int j=0;j<5;j++) a[i*5+j]+=R[i]*P[j];
    int k=20;
    #pragma unroll
    for (int i=0;i<5;i++)
      #pragma unroll
      for (int j=i;j<5;j++){ a[k]+=P[i]*P[j]; k++; }
  }
  __shared__ float red[35*4];
  float lo[20], hi[15];
  #pragma unroll
  for (int k=0;k<20;k++) lo[k]=a[k];
  #pragma unroll
  for (int k=0;k<15;k++) hi[k]=a[20+k];
  blockAccumN<20>(S+280, lo, red);
  blockAccumN<15>(S+300, hi, red);
}
__global__ void k_lowstats(const float2* __restrict__ lp, double* S){
  __shared__ float red[4];
  __shared__ float smu;
  int lane=threadIdx.x&63, wid=threadIdx.x>>6;
  float s=0.f;
  for (int i=threadIdx.x;i<4096;i+=256) s+=lp[i].x;
  for (int o=32;o>0;o>>=1) s+=__shfl_down(s,o);
  if (lane==0) red[wid]=s;
  __syncthreads();
  if (threadIdx.x==0){
    float t=red[0]+red[1]+red[2]+red[3];
    S[22]=(double)t; smu=t/4096.f;
  }
  __syncthreads();
  float mu=smu, ad=0.f;
  for (int i=threadIdx.x;i<4096;i+=256) ad+=fabsf(lp[i].x-mu);
  for (int o=32;o>0;o>>=1) ad+=__shfl_down(ad,o);
  if (lane==0) red[wid]=ad;
  __syncthreads();
  if (threadIdx.x==0) S[23]=(double)(red[0]+red[1]+red[2]+red[3]);
}
__global__ void k_imlpstats(const float2* __restrict__ ip, double* Smom, double* Sac){
  __shared__ float t[64][65];
  for (int i=threadIdx.x;i<4096;i+=256) t[i>>6][i&63]=ip[i].x;
  __syncthreads();
  float s2=0.f,s3=0.f,s4=0.f;
  float acc[41];
  #pragma unroll
  for (int k=0;k<41;k++) acc[k]=0.f;
  for (int p=threadIdx.x;p<4096;p+=256){
    int y=p>>6, x=p&63;
    float m0=t[y][x], m02=m0*m0;
    s2+=m02; s3+=m02*m0; s4+=m02*m02;
    #pragma unroll
    for (int dj=1;dj<=4;dj++)
      #pragma unroll
      for (int di=-4;di<=4;di++)
        acc[(dj-1)*9+di+4] += m0 * t[(y+di)&63][(x+dj)&63];
    #pragma unroll
    for (int di=0;di<=4;di++)
      acc[36+di] += m0 * t[(y+di)&63][x];
  }
  __shared__ float red[41*4];
  float mom[3]={s2,s3,s4};
  blockAccumN<3>(Smom, mom, red);
  blockAccumN<41>(Sac, acc, red);
}

__global__ void k_final(const double* __restrict__ S, const float* __restrict__ PB, float* out){
  const int tid = threadIdx.x;
  const double N0 = 1048576.0;
  const double npix[4]={1048576.0,262144.0,65536.0,16384.0};
  __shared__ double sh[6];

  // phase A: reduce imgstats partials (256 rows x {s1,s2,s3,s4,mn,mx})
  {
    __shared__ double wrD[4][4];
    __shared__ float  wrF[2][4];
    int lane=tid&63, wid=tid>>6;
    double p[4]; float pn, px;
    #pragma unroll
    for (int k=0;k<4;k++) p[k]=(double)PB[tid*8+k];
    pn=PB[tid*8+4]; px=PB[tid*8+5];
    #pragma unroll
    for (int k=0;k<4;k++){
      double v=p[k];
      for (int o=32;o>0;o>>=1) v+=__shfl_down(v,o);
      if (lane==0) wrD[k][wid]=v;
    }
    { float v=pn; for (int o=32;o>0;o>>=1) v=fminf(v,__shfl_down(v,o)); if(lane==0) wrF[0][wid]=v; }
    { float v=px; for (int o=32;o>0;o>>=1) v=fmaxf(v,__shfl_down(v,o)); if(lane==0) wrF[1][wid]=v; }
    __syncthreads();
    if (tid==0){
      for (int k=0;k<4;k++) sh[k]=wrD[k][0]+wrD[k][1]+wrD[k][2]+wrD[k][3];
      sh[4]=(double)fminf(fminf(wrF[0][0],wrF[0][1]),fminf(wrF[0][2],wrF[0][3]));
      sh[5]=(double)fmaxf(fmaxf(wrF[1][0],wrF[1][1]),fmaxf(wrF[1][2],wrF[1][3]));
    }
    __syncthreads();
  }
  #define G(k) (S[0*SL_TOT+(k)]+S[1*SL_TOT+(k)]+S[2*SL_TOT+(k)]+S[3*SL_TOT+(k)] \
               +S[4*SL_TOT+(k)]+S[5*SL_TOT+(k)]+S[6*SL_TOT+(k)]+S[7*SL_TOT+(k)])

  for (int e=tid; e<81*16; e+=256){
    int w=e>>4, s=(e>>2)&3, b=e&3;
    int i=w/9, j=w-i*9;
    int k=lagIdx(i-4,j-4);
    double n2=npix[s];
    double mu=G(6+s*4+b)/n2;
    out[24+(w*4+s)*4+b]=(float)(G(SL_ACE+(s*4+b)*41+k)/n2 - mu*mu);
  }
  for (int e=tid; e<81*4; e+=256){
    int w=e>>2, s=e&3;
    int i=w/9, j=w-i*9;
    int k=lagIdx(i-4,j-4);
    out[1330+w*5+s]=(float)(G(SL_ACR+s*41+k)/(2.0*npix[s]));
  }
  for (int w=tid; w<81; w+=256){
    int i=w/9, j=w-i*9;
    int k=lagIdx(i-4,j-4);
    out[1330+w*5+4]=(float)(G(SL_ALP+k)/4096.0);
  }
  if (tid==0){
    double sum=sh[0], s2=sh[1], s3=sh[2], s4=sh[3];
    double mean0=sum/N0;
    double var0=(s2 - sum*mean0)/(N0-1.0);
    double m3 = s3 - 3.0*mean0*s2 + 2.0*N0*mean0*mean0*mean0;
    double m4 = s4 - 4.0*mean0*s3 + 6.0*mean0*mean0*s2 - 3.0*N0*mean0*mean0*mean0*mean0;
    out[0]=(float)mean0; out[1]=(float)var0;
    out[2]=(float)((m3/N0)/(var0*sqrt(var0)));
    out[3]=(float)((m4/N0)/(var0*var0));
    out[4]=(float)sh[4]; out[5]=(float)sh[5];
    out[6]=(float)(G(4)/N0);
    for (int s=0;s<4;s++) for (int b=0;b<4;b++) out[7+s*4+b]=(float)(G(6+s*4+b)/npix[s]);
    out[23]=(float)(G(23)/4096.0);
    for (int s=0;s<4;s++){
      double n2=npix[s];
      double vari=G(24+s*3)/(2.0*n2);
      int ok=(vari/var0>1e-6);
      out[1320+s]= ok? (float)(0.5*(G(25+s*3)/n2)/(vari*sqrt(vari))) : 0.f;
      out[1325+s]= ok? (float)(0.5*(G(26+s*3)/n2)/(vari*vari)) : 3.f;
    }
    { double vari=G(36)/4096.0; int ok=(vari/var0>1e-6);
      out[1324]= ok? (float)((G(37)/4096.0)/(vari*sqrt(vari))) : 0.f;
      out[1329]= ok? (float)((G(38)/4096.0)/(vari*vari)) : 3.f; }
    for (int s=0;s<4;s++){
      double n2=npix[s];
      for (int i=0;i<4;i++) for (int j=0;j<4;j++){
        int a2=i<j?i:j, bb=i<j?j:i;
        int p=a2*(7-a2)/2+bb;
        double Si=G(6+s*4+i), Sj=G(6+s*4+j);
        out[1735+(i*4+j)*5+s]=(float)((G(40+s*20+p)-Si*Sj/n2)/n2);
        out[1879+(i*8+j)*5+s]=(float)(G(40+s*20+10+p)/n2);
      }
    }
    for (int s=0;s<3;s++){
      double n2=npix[s];
      for (int j=0;j<4;j++){
        int pb=120+(s*4+j)*13;
        double Smj=G(pb);
        for (int i=0;i<4;i++){
          double Si=G(6+s*4+i);
          out[1815+(i*4+j)*4+s]=(float)((G(pb+1+i)-Si*Smj/n2)/n2);
          out[2199+(i*8+j)*4+s]=(float)(G(pb+5+i)/n2);
          out[2199+(i*8+(j+4))*4+s]=(float)(G(pb+9+i)/n2);
        }
      }
    }
    for (int i=0;i<4;i++) for (int j=0;j<5;j++)
      out[2199+(i*8+j)*4+3]=(float)(G(280+i*5+j)/16384.0);
    for (int i=0;i<5;i++) for (int j=0;j<5;j++){
      int a2=i<j?i:j, bb=i<j?j:i;
      int p=a2*(9-a2)/2+bb;
      out[1879+(i*8+j)*5+4]=(float)(G(300+p)/4096.0);
    }
    out[2455]=(float)(G(5)/N0);
  }
  #undef G
}

// ---------------- host orchestration -----------------------------------------
template<int PRE,int POST>
static void lfft(int n, int nimg, FArgs a, hipStream_t st){
  switch(n){
    case 1024: k_fft<1024,PRE,POST><<<dim3(1024,nimg),fftT(1024),0,st>>>(a); break;
    case 512:  k_fft<512 ,PRE,POST><<<dim3(512 ,nimg),fftT(512 ),0,st>>>(a); break;
    case 256:  k_fft<256 ,PRE,POST><<<dim3(256 ,nimg),fftT(256 ),0,st>>>(a); break;
    case 128:  k_fft<128 ,PRE,POST><<<dim3(128 ,nimg),fftT(128 ),0,st>>>(a); break;
    case 64:   k_fft<64  ,PRE,POST><<<dim3(64  ,nimg),fftT(64  ),0,st>>>(a); break;
  }
}

extern "C" void kernel_launch(void* const* d_in, const int* in_sizes, int n_in,
                              void* d_out, int out_size, void* d_ws, size_t ws_size,
                              hipStream_t stream){
  const float* im = (const float*)d_in[0];
  float* out = (float*)d_out;
  char* w = (char*)d_ws;
  float2* CA4 = (float2*)w;                              // 32 MB: 4 bands
  float2* CB4 = (float2*)(w + ((size_t)32<<20));         // 16 MB: scratch
  float2* CC  = (float2*)(w + ((size_t)48<<20));         // 8 MB: unor / tails
  size_t off = (size_t)56<<20;
  float2* LOD[5]; int lsz[5]={1024,512,256,128,64};
  for (int i=0;i<5;i++){ LOD[i]=(float2*)(w+off); off += (size_t)lsz[i]*lsz[i]*8; }
  off = (off + 255) & ~(size_t)255;
  double* S = (double*)(w+off);                          // REP*SL_TOT doubles
  float* PB = (float*)(w+off+(size_t)REP*SL_TOT*8);      // 256*8 floats

  k_init<<<40,256,0,stream>>>(S,out,2456);
  k_imgstats<<<256,256,0,stream>>>((const float4*)im,PB);

  FArgs a{};
  // forward fft2 (3 passes) -> F^T in CA4
  a = FArgs{}; a.rsrc=im; a.dst=CA4; a.dirsign=-1.f; a.scale=1.f;
  lfft<1,0>(1024,1,a,stream);
  k_trip<<<dim3(32,32,1),dim3(32,8),0,stream>>>(CA4,1024);
  a = FArgs{}; a.src=CA4; a.dst=CA4; a.dirsign=-1.f; a.scale=1.f;
  lfft<0,0>(1024,1,a,stream);
  // split (lo0 -> LOD[0], hi -> chain) + hi0 ifft2 + |.|,^2 sums
  a = FArgs{}; a.src=CA4; a.dst=CB4; a.aux2=LOD[0]; a.dirsign=1.f; a.scale=1.f/1024.f;
  lfft<9,0>(1024,1,a,stream);
  k_trip<<<dim3(32,32,1),dim3(32,8),0,stream>>>(CB4,1024);
  a = FArgs{}; a.src=CB4; a.dst=CB4; a.slots=S+4; a.dirsign=1.f; a.scale=1.f/1024.f;
  lfft<0,1>(1024,1,a,stream);

  for (int s=0;s<4;s++){
    const int n=1024>>s, nt=n/32, n2=n*n, lg=10-s;
    const float inv = 1.f/(float)n;
    // bands (batched over 4)
    a = FArgs{}; a.src=LOD[s]; a.dst=CA4; a.b0=0; a.dirsign=1.f; a.scale=inv;
    lfft<2,0>(n,4,a,stream);
    k_trip<<<dim3(nt,nt,4),dim3(32,8),0,stream>>>(CA4,n);
    a = FArgs{}; a.src=CA4; a.dst=CA4; a.slots=S+6+s*4; a.dirsign=1.f; a.scale=inv;
    lfft<0,2>(n,4,a,stream);
    k_gram<<<256,256,0,stream>>>(CA4,n2,S+40+s*20);
    k_ac<0><<<dim3(n/64,n/64,4),256,0,stream>>>(CA4,n,lg,n2,S+SL_ACE+(size_t)(s*4)*41);
    // unor
    a = FArgs{}; a.src=LOD[s]; a.dst=CC; a.dirsign=1.f; a.scale=inv;
    lfft<3,0>(n,1,a,stream);
    k_trip<<<dim3(nt,nt,1),dim3(32,8),0,stream>>>(CC,n);
    a = FArgs{}; a.src=CC; a.dst=CC; a.slots=S+24+s*3; a.dirsign=1.f; a.scale=inv;
    lfft<0,3>(n,1,a,stream);
    k_ac<1><<<dim3(n/64,n/64,1),256,0,stream>>>(CC,n,lg,n2,S+SL_ACR+(size_t)s*41);
    // next lodft
    int nn=n>>1;
    k_croplo<<<dim3(nn*nn/256),256,0,stream>>>(LOD[s],LOD[s+1],nn,lg-1);
    if (s<3){
      const int nb = (s==0)? 2 : 4;
      for (int b0=0;b0<4;b0+=nb){
        a = FArgs{}; a.src=LOD[s+1]; a.dst=CB4; a.b0=b0; a.dirsign=1.f; a.scale=inv;
        lfft<4,0>(n,nb,a,stream);
        k_trip<<<dim3(nt,nt,nb),dim3(32,8),0,stream>>>(CB4,n);
        a = FArgs{}; a.src=CB4; a.dst=CB4; a.aux=CA4;
        a.slots=S+120+(size_t)(s*4+b0)*13; a.dirsign=1.f; a.scale=inv;
        lfft<0,4>(n,nb,a,stream);
      }
    } else {
      float2* LPB=CC; float2* IMB=CC+4096; float2* RPB=CC+8192;
      // lowpass
      a = FArgs{}; a.src=LOD[4]; a.dst=LPB; a.dirsign=1.f; a.scale=1.f/64.f;
      lfft<0,0>(64,1,a,stream);
      k_trip<<<dim3(2,2,1),dim3(32,8),0,stream>>>(LPB,64);
      a = FArgs{}; a.src=LPB; a.dst=LPB; a.dirsign=1.f; a.scale=1.f/64.f;
      lfft<0,0>(64,1,a,stream);
      k_lowstats<<<1,256,0,stream>>>(LPB,S);
      // imlp
      a = FArgs{}; a.src=LOD[4]; a.dst=IMB; a.dirsign=1.f; a.scale=1.f/64.f;
      lfft<7,0>(64,1,a,stream);
      k_trip<<<dim3(2,2,1),dim3(32,8),0,stream>>>(IMB,64);
      a = FArgs{}; a.src=IMB; a.dst=IMB; a.dirsign=1.f; a.scale=1.f/64.f;
      lfft<0,0>(64,1,a,stream);
      k_imlpstats<<<1,256,0,stream>>>(IMB,S+36,S+SL_ALP);
      // rparents (expanded lowpass) + crx3
      a = FArgs{}; a.src=LOD[4]; a.dst=RPB; a.dirsign=1.f; a.scale=1.f/128.f;
      lfft<5,0>(128,1,a,stream);
      k_trip<<<dim3(4,4,1),dim3(32,8),0,stream>>>(RPB,128);
      a = FArgs{}; a.src=RPB; a.dst=RPB; a.dirsign=1.f; a.scale=1.f/128.f;
      lfft<0,0>(128,1,a,stream);
      k_crx3<<<64,256,0,stream>>>(RPB,CA4,S);
    }
  }
  k_final<<<1,256,0,stream>>>(S,PB,out);
  (void)in_sizes; (void)n_in; (void)out_size; (void)ws_size;
}

// Round 6
// 535.128 us; speedup vs baseline: 9.8019x; 1.3296x over previous
//
#include <hip/hip_runtime.h>

#define PI_F     3.14159265358979323846f
#define TWOPI_F  6.28318530717958647692f
#define HPI_F    1.57079632679489661923f

constexpr int fftT(int N){ return N>=512 ? 256 : (N/2 < 64 ? 64 : N/2); }

// S-slot layout (doubles), replicated REP times (replica stride SL_TOT)
#define SL_ACE 340          // 16 x 41
#define SL_ACR 996          // 4 x 41
#define SL_ALP 1160         // 41
#define SL_TOT 1280
#define REP 8

__device__ __forceinline__ float fcoord(int k, int n){
  int s = k ^ (n>>1);
  return (float)(s - (n>>1)) / (float)(n>>1);
}
__device__ __forceinline__ float lograd(int kr, int kc, int n){
  if (kr==0 && kc==0) return log2f(2.0f/(float)n);
  float x = fcoord(kc,n), y = fcoord(kr,n);
  return 0.5f*log2f(x*x+y*y);
}
__device__ __forceinline__ float rc_sin(float lr, float shift){
  float t = fminf(fmaxf(lr+shift,0.f),1.f); return __sinf(HPI_F*t);
}
__device__ __forceinline__ float rc_cos(float lr, float shift){
  float t = fminf(fmaxf(lr+shift,0.f),1.f); return __cosf(HPI_F*t);
}
// cumulative lowpass mask to reach scale s: prod_{m=0..s} rc_cos(lr, 1-m)
__device__ __forceinline__ float cumlo(float lr, int s){
  float cl = rc_cos(lr, 1.f);
  for (int m=1;m<=s;m++) cl *= rc_cos(lr, 1.f-(float)m);
  return cl;
}
__device__ __forceinline__ float bandmask(int kr, int kc, int n, int b){
  float x = fcoord(kc,n), y = fcoord(kr,n);
  float ang = atan2f(y,x);
  float lr = lograd(kr,kc,n);
  float him = rc_sin(lr,2.0f);
  float th = ang - 0.25f*PI_F*(float)b;
  float u = th + PI_F;
  u -= TWOPI_F*floorf(u*(1.0f/TWOPI_F));
  float thw = u - PI_F;
  float c = __cosf(th);
  float am = (fabsf(thw) < HPI_F) ? (1.7888543819998317f*c*c*c) : 0.0f;
  return am*him;
}
__device__ __forceinline__ int lagIdx(int di, int dj){
  if (dj < 0 || (dj==0 && di<0)){ di=-di; dj=-dj; }
  return dj==0 ? 36+di : (dj-1)*9 + (di+4);
}
__device__ __forceinline__ void atomAddD(double* p, double v){
  unsafeAtomicAdd(p, v);
}
template<int NS>
__device__ __forceinline__ void blockAccumN(double* base, const float* vals, float* red){
  const int lane = threadIdx.x & 63, wid = threadIdx.x >> 6;
  const int nw = (int)(blockDim.x >> 6);
  #pragma unroll
  for (int k=0;k<NS;k++){
    float v = vals[k];
    #pragma unroll
    for (int o=32;o>0;o>>=1) v += __shfl_down(v,o);
    if (lane==0) red[k*nw+wid]=v;
  }
  __syncthreads();
  const int rep = (int)((blockIdx.x ^ (blockIdx.y<<1) ^ (blockIdx.z<<2)) & 7) * SL_TOT;
  if ((int)threadIdx.x < NS){
    float s=0.f;
    for (int w2=0;w2<nw;w2++) s += red[(int)threadIdx.x*nw+w2];
    atomAddD(base+rep+(int)threadIdx.x,(double)s);
  }
  __syncthreads();
}

// ---------------- batched descriptor FFT -------------------------------------
// pre: 0 cplx slab, 1 real row, 2 band from F, 3 him from F, 4 hi0 from F,
//      5 padband from F, 6 padlp from F
// post: 0 store, 1 sum|x|,x^2, 2 store+summag, 3 store+moments, 4 parentred
struct ImgD { const float2* src; float2* dst; double* slots; int pre, post, b, ss; float scale; };
struct BArgs { ImgD img[6]; const float* rsrc; const float2* F; const float2* aux; float dirsign; };

#define TWI(k) ((k)+((k)>>4))

template<int N>
__global__ __launch_bounds__(fftT(N)) void k_fftB(BArgs a){
  constexpr int T = fftT(N);
  constexpr int LG = (N==1024)?10:(N==512)?9:(N==256)?8:(N==128)?7:6;
  __shared__ float2 sm[2][N];
  __shared__ float2 tw[N/2 + N/32];
  __shared__ float red[13*4];
  const ImgD d = a.img[blockIdx.y];
  const int row = blockIdx.x, tid = threadIdx.x;
  bool zrow=false;

  for (int k=tid;k<N/2;k+=T){
    float sn,cs; __sincosf(TWOPI_F*(float)k/(float)N,&sn,&cs);
    tw[TWI(k)]=make_float2(cs,sn);
  }

  switch(d.pre){
    case 0: {
      const float2* sp = d.src + (size_t)row*N;
      for (int i=tid;i<N;i+=T) sm[0][i]=sp[i];
    } break;
    case 1: {
      const float* rp = a.rsrc + (size_t)row*N;
      for (int i=tid;i<N;i+=T) sm[0][i]=make_float2(rp[i],0.f);
    } break;
    case 2: {
      const int KC = row + ((row < N/2)? 0 : (1024-N));
      const float2* Fr = a.F + (size_t)KC*1024;
      for (int i=tid;i<N;i+=T){
        int KR = i + ((i < N/2)? 0 : (1024-N));
        float2 v = Fr[KR];
        float lr = lograd(i,row,N);
        float m = cumlo(lr,d.ss)*bandmask(i,row,N,d.b);
        sm[0][i]=make_float2(-v.y*m, v.x*m);   // (-1j)^3 = +i
      }
    } break;
    case 3: {
      const int KC = row + ((row < N/2)? 0 : (1024-N));
      const float2* Fr = a.F + (size_t)KC*1024;
      for (int i=tid;i<N;i+=T){
        int KR = i + ((i < N/2)? 0 : (1024-N));
        float2 v = Fr[KR];
        float lr = lograd(i,row,N);
        float m = cumlo(lr,d.ss)*rc_sin(lr,2.f);
        sm[0][i]=make_float2(v.x*m, v.y*m);
      }
    } break;
    case 4: {
      const float2* Fr = a.F + (size_t)row*1024;
      for (int i=tid;i<N;i+=T){
        float2 v = Fr[i];
        float m = rc_sin(lograd(i,row,N),1.f);
        sm[0][i]=make_float2(v.x*m, v.y*m);
      }
    } break;
    case 5: case 6: {
      constexpr int M=N/2, Q=N/4;
      const int fi = (row<Q)? row : (row>=N-Q ? row-M : -1);
      if (fi<0){
        for (int i=tid;i<N;i+=T) sm[0][i]=make_float2(0.f,0.f);
        zrow=true;
      } else {
        const int KC = fi + ((fi < M/2)? 0 : (1024-M));
        const float2* Fr = a.F + (size_t)KC*1024;
        for (int i=tid;i<N;i+=T){
          int fj = (i<Q)? i : (i>=N-Q ? i-M : -1);
          float2 r = make_float2(0.f,0.f);
          if (fj>=0){
            int KR = fj + ((fj < M/2)? 0 : (1024-M));
            float2 v = Fr[KR];
            float lr = lograd(fj,fi,M);
            if (d.pre==5){
              float m = cumlo(lr,d.ss+1)*bandmask(fj,fi,M,d.b);
              r = make_float2(-v.y*m, v.x*m);
            } else {
              if (!(fi==0 && fj==0)){
                float m = cumlo(lr,4);
                r = make_float2(v.x*m, v.y*m);
              }
            }
          }
          sm[0][i]=r;
        }
      }
    } break;
  }

  int cur=0;
  if (!zrow){
    const float ds = a.dirsign;
    for (int ls=0; ls<LG; ++ls){
      const int Ns=1<<ls, sh=LG-1-ls;
      __syncthreads();
      for (int j=tid; j<N/2; j+=T){
        const int m = j & (Ns-1);
        const int base = ((j>>ls)<<(ls+1)) + m;
        float2 va = sm[cur][j];
        float2 vb = sm[cur][j+N/2];
        float2 w = tw[TWI(m<<sh)];
        float wy = ds*w.y;
        float2 bw = make_float2(vb.x*w.x - vb.y*wy, vb.x*wy + vb.y*w.x);
        sm[cur^1][base]    = make_float2(va.x+bw.x, va.y+bw.y);
        sm[cur^1][base+Ns] = make_float2(va.x-bw.x, va.y-bw.y);
      }
      cur ^= 1;
    }
  }
  __syncthreads();

  const float sc = d.scale;
  switch(d.post){
    case 0: {
      float2* dp = d.dst + (size_t)row*N;
      for (int i=tid;i<N;i+=T){ float2 v=sm[cur][i]; dp[i]=make_float2(v.x*sc,v.y*sc); }
    } break;
    case 1: {
      float a1=0.f,a2=0.f;
      for (int i=tid;i<N;i+=T){ float v=sm[cur][i].x*sc; a1+=fabsf(v); a2+=v*v; }
      float vals[2]={a1,a2};
      blockAccumN<2>(d.slots, vals, red);
    } break;
    case 2: {
      float2* dp = d.dst + (size_t)row*N;
      float am=0.f;
      for (int i=tid;i<N;i+=T){
        float2 v=sm[cur][i]; v.x*=sc; v.y*=sc; dp[i]=v;
        am += sqrtf(v.x*v.x+v.y*v.y);
      }
      float vals[1]={am};
      blockAccumN<1>(d.slots, vals, red);
    } break;
    case 3: {
      float2* dp = d.dst + (size_t)row*N;
      float s2=0.f,s3=0.f,s4=0.f;
      for (int i=tid;i<N;i+=T){
        float2 v=sm[cur][i]; v.x*=sc; v.y*=sc; dp[i]=v;
        float x=v.x, x2=x*x; s2+=x2; s3+=x2*x; s4+=x2*x2;
      }
      float vals[3]={s2,s3,s4};
      blockAccumN<3>(d.slots, vals, red);
    } break;
    case 4: {
      const float2* B = a.aux;
      constexpr size_t N2 = (size_t)N*N;
      float acc[13];
      #pragma unroll
      for (int k=0;k<13;k++) acc[k]=0.f;
      for (int i=tid;i<N;i+=T){
        float2 p=sm[cur][i]; p.x*=sc; p.y*=sc;
        float m = sqrtf(p.x*p.x+p.y*p.y);
        float rp=0.f, ip=0.f;
        if (m>0.f){ rp=(p.y*p.y-p.x*p.x)/m; ip=2.f*p.x*p.y/m; }
        size_t pos = (size_t)row*N + i;
        acc[0]+=m;
        #pragma unroll
        for (int k=0;k<4;k++){
          float2 z = B[k*N2+pos];
          float mk = sqrtf(z.x*z.x+z.y*z.y);
          acc[1+k]+=mk*m; acc[5+k]+=z.x*rp; acc[9+k]+=z.x*ip;
        }
      }
      blockAccumN<13>(d.slots, acc, red);
    } break;
  }
}

// multi-base in-place batched square transpose
struct TArgs { float2* base[6]; int n; };
__global__ void k_trip(TArgs t){
  int bi = blockIdx.x, bj = blockIdx.y;
  if (bj < bi) return;
  const int n = t.n;
  float2* img = t.base[blockIdx.z];
  __shared__ float2 t0[32][33], t1[32][33];
  int r0=bi*32, c0=bj*32;
  for (int dy=threadIdx.y; dy<32; dy+=8){
    t0[dy][threadIdx.x] = img[(size_t)(r0+dy)*n + c0 + threadIdx.x];
    if (bi!=bj) t1[dy][threadIdx.x] = img[(size_t)(c0+dy)*n + r0 + threadIdx.x];
  }
  __syncthreads();
  for (int dy=threadIdx.y; dy<32; dy+=8){
    img[(size_t)(c0+dy)*n + r0 + threadIdx.x] = t0[threadIdx.x][dy];
    if (bi!=bj) img[(size_t)(r0+dy)*n + c0 + threadIdx.x] = t1[threadIdx.x][dy];
  }
}

// multi-base direct circular autocorrelation (41 unique 9x9 lags)
struct AArgs { const float2* base[5]; double* slots[5]; int n, lgn, nmag; };
__global__ __launch_bounds__(256) void k_ac(AArgs a){
  __shared__ float t[72][73];
  __shared__ float red[41*4];
  const int z = blockIdx.z;
  const float2* img = a.base[z];
  const bool mag = z < a.nmag;
  const int n = a.n, lgn = a.lgn;
  const int ty0 = blockIdx.y*64, tx0 = blockIdx.x*64;
  for (int idx = threadIdx.x; idx < 72*72; idx += 256){
    int ly = idx/72, lx = idx-ly*72;
    int gy = (ty0 + ly - 4) & (n-1), gx = (tx0 + lx - 4) & (n-1);
    float2 v = img[((size_t)gy<<lgn) + gx];
    t[ly][lx] = mag ? sqrtf(v.x*v.x+v.y*v.y) : v.x;
  }
  __syncthreads();
  float acc[41];
  #pragma unroll
  for (int k=0;k<41;k++) acc[k]=0.f;
  for (int p = threadIdx.x; p < 4096; p += 256){
    int ly = (p>>6) + 4, lx = (p&63) + 4;
    float m0 = t[ly][lx];
    #pragma unroll
    for (int dj=1; dj<=4; dj++)
      #pragma unroll
      for (int di=-4; di<=4; di++)
        acc[(dj-1)*9 + di+4] += m0 * t[ly+di][lx+dj];
    #pragma unroll
    for (int di=0; di<=4; di++)
      acc[36+di] += m0 * t[ly+di][lx];
  }
  blockAccumN<41>(a.slots[z], acc, red);
}

// ---------------- misc kernels ----------------------------------------------
__global__ void k_init(double* S, float* out, int nout){
  int i = blockIdx.x*blockDim.x + threadIdx.x;
  if (i < REP*SL_TOT) S[i]=0.0;
  if (i < nout) out[i]=0.f;
}
__global__ __launch_bounds__(256) void k_imgstats(const float4* __restrict__ x, float* PB){
  float s1=0.f,s2=0.f,s3=0.f,s4=0.f, mn=3.4e38f, mx=-3.4e38f;
  const int base = blockIdx.x*1024 + threadIdx.x;
  #pragma unroll
  for (int it=0; it<4; ++it){
    float4 v = x[base + it*256];
    float vs[4]={v.x,v.y,v.z,v.w};
    #pragma unroll
    for (int k=0;k<4;k++){
      float t=vs[k], t2=t*t;
      s1+=t; s2+=t2; s3+=t2*t; s4+=t2*t2;
      mn=fminf(mn,t); mx=fmaxf(mx,t);
    }
  }
  __shared__ float wr[6][4];
  int lane=threadIdx.x&63, wid=threadIdx.x>>6;
  float sums[4]={s1,s2,s3,s4};
  #pragma unroll
  for (int k=0;k<4;k++){
    float v=sums[k];
    for (int o=32;o>0;o>>=1) v+=__shfl_down(v,o);
    if (lane==0) wr[k][wid]=v;
  }
  { float v=mn; for (int o=32;o>0;o>>=1) v=fminf(v,__shfl_down(v,o)); if(lane==0) wr[4][wid]=v; }
  { float v=mx; for (int o=32;o>0;o>>=1) v=fmaxf(v,__shfl_down(v,o)); if(lane==0) wr[5][wid]=v; }
  __syncthreads();
  if (threadIdx.x<4)  PB[blockIdx.x*8+threadIdx.x] = wr[threadIdx.x][0]+wr[threadIdx.x][1]+wr[threadIdx.x][2]+wr[threadIdx.x][3];
  if (threadIdx.x==4) PB[blockIdx.x*8+4] = fminf(fminf(wr[4][0],wr[4][1]),fminf(wr[4][2],wr[4][3]));
  if (threadIdx.x==5) PB[blockIdx.x*8+5] = fmaxf(fmaxf(wr[5][0],wr[5][1]),fmaxf(wr[5][2],wr[5][3]));
}
__global__ void k_gram(const float2* __restrict__ B, int n2, double* slots){
  float p[20];
  #pragma unroll
  for (int i=0;i<20;i++) p[i]=0.f;
  int stride = gridDim.x*blockDim.x;
  for (int i=blockIdx.x*blockDim.x+threadIdx.x; i<n2; i+=stride){
    float2 z0=B[i], z1=B[i+(size_t)n2], z2=B[i+2*(size_t)n2], z3=B[i+3*(size_t)n2];
    float m0=sqrtf(z0.x*z0.x+z0.y*z0.y), m1=sqrtf(z1.x*z1.x+z1.y*z1.y);
    float m2=sqrtf(z2.x*z2.x+z2.y*z2.y), m3=sqrtf(z3.x*z3.x+z3.y*z3.y);
    float r0=z0.x, r1=z1.x, r2=z2.x, r3=z3.x;
    p[0]+=m0*m0; p[1]+=m0*m1; p[2]+=m0*m2; p[3]+=m0*m3;
    p[4]+=m1*m1; p[5]+=m1*m2; p[6]+=m1*m3;
    p[7]+=m2*m2; p[8]+=m2*m3; p[9]+=m3*m3;
    p[10]+=r0*r0; p[11]+=r0*r1; p[12]+=r0*r2; p[13]+=r0*r3;
    p[14]+=r1*r1; p[15]+=r1*r2; p[16]+=r1*r3;
    p[17]+=r2*r2; p[18]+=r2*r3; p[19]+=r3*r3;
  }
  __shared__ float red[20*4];
  blockAccumN<20>(slots,p,red);
}
__global__ void k_crx3(const float2* __restrict__ RP, const float2* __restrict__ B3, double* S){
  float a[35];
  #pragma unroll
  for (int i=0;i<35;i++) a[i]=0.f;
  int stride = gridDim.x*blockDim.x;
  for (int idx=blockIdx.x*blockDim.x+threadIdx.x; idx<16384; idx+=stride){
    int u=idx>>7, v=idx&127;
    float P0=RP[idx].x;
    float P1=RP[(u<<7) | ((v-1)&127)].x;
    float P2=RP[(u<<7) | ((v+1)&127)].x;
    float P3=RP[(((u-1)&127)<<7) | v].x;
    float P4=RP[(((u+1)&127)<<7) | v].x;
    float P[5]={P0,P1,P2,P3,P4};
    float R[4];
    #pragma unroll
    for (int b=0;b<4;b++) R[b]=B3[b*16384 + (v<<7) + u].x;
    #pragma unroll
    for (int i=0;i<4;i++)
      #pragma unroll
      for (int j=0;j<5;j++) a[i*5+j]+=R[i]*P[j];
    int k=20;
    #pragma unroll
    for (int i=0;i<5;i++)
      #pragma unroll
      for (int j=i;j<5;j++){ a[k]+=P[i]*P[j]; k++; }
  }
  __shared__ float red[35*4];
  float lo[20], hi[15];
  #pragma unroll
  for (int k=0;k<20;k++) lo[k]=a[k];
  #pragma unroll
  for (int k=0;k<15;k++) hi[k]=a[20+k];
  blockAccumN<20>(S+280, lo, red);
  blockAccumN<15>(S+300, hi, red);
}

// in-place unnormalized inverse 2D FFT in LDS, separated planes, stride S
template<int LG>
__device__ void ifft2_lds(float* re, float* im, const float2* tw, int S){
  constexpr int N=1<<LG, H=N>>1;
  const int tid=threadIdx.x, T=256;
  for (int ls=LG-1; ls>=0; --ls){
    const int h=1<<ls;
    __syncthreads();
    for (int t=tid; t<N*H; t+=T){
      int r=t>>(LG-1), j=t&(H-1);
      int m=j&(h-1);
      int i0=r*S + ((j>>ls)<<(ls+1)) + m, i1=i0+h;
      float ar=re[i0], ai=im[i0], br=re[i1], bi=im[i1];
      re[i0]=ar+br; im[i0]=ai+bi;
      float dr=ar-br, di=ai-bi;
      float2 w=tw[m<<(LG-1-ls)];
      re[i1]=dr*w.x - di*w.y;
      im[i1]=dr*w.y + di*w.x;
    }
  }
  __syncthreads();
  for (int t=tid;t<N*N;t+=T){
    int r=t>>LG, j=t&(N-1);
    int jb=(int)(__brev((unsigned)j)>>(32-LG));
    if (j<jb){
      int p=r*S+j, q=r*S+jb;
      float x=re[p]; re[p]=re[q]; re[q]=x;
      x=im[p]; im[p]=im[q]; im[q]=x;
    }
  }
  for (int ls=LG-1; ls>=0; --ls){
    const int h=1<<ls;
    __syncthreads();
    for (int t=tid; t<N*H; t+=T){
      int c=t>>(LG-1), j=t&(H-1);
      int m=j&(h-1);
      int i0=(((j>>ls)<<(ls+1))+m)*S + c, i1=i0+h*S;
      float ar=re[i0], ai=im[i0], br=re[i1], bi=im[i1];
      re[i0]=ar+br; im[i0]=ai+bi;
      float dr=ar-br, di=ai-bi;
      float2 w=tw[m<<(LG-1-ls)];
      re[i1]=dr*w.x - di*w.y;
      im[i1]=dr*w.y + di*w.x;
    }
  }
  __syncthreads();
  for (int t=tid;t<N*N;t+=T){
    int c=t>>LG, j=t&(N-1);
    int jb=(int)(__brev((unsigned)j)>>(32-LG));
    if (j<jb){
      int p=j*S+c, q=jb*S+c;
      float x=re[p]; re[p]=re[q]; re[q]=x;
      x=im[p]; im[p]=im[q]; im[q]=x;
    }
  }
  __syncthreads();
}

// fused 64x64 tail: lowpass (absdev) + imlp (moments + 41-lag AC)
__global__ __launch_bounds__(256) void k_tail64(const float2* __restrict__ F, double* S){
  __shared__ float re[64*65];
  __shared__ float im[64*65];
  __shared__ float2 tw[32];
  __shared__ float red[41*4];
  __shared__ float shmu;
  const int tid=threadIdx.x;
  const float sc=1.f/4096.f;
  for (int k=tid;k<32;k+=256){
    float sn,cs; __sincosf(TWOPI_F*(float)k/64.f,&sn,&cs);
    tw[k]=make_float2(cs,sn);
  }
  // ---- lowpass ----
  for (int t=tid;t<4096;t+=256){
    int a2=t>>6, b=t&63;
    int KR = b + ((b<32)?0:960);
    int KC = a2 + ((a2<32)?0:960);
    float2 v = F[(size_t)KC*1024+KR];
    float m = cumlo(lograd(b,a2,64),4);
    re[a2*65+b]=v.x*m; im[a2*65+b]=v.y*m;
  }
  ifft2_lds<6>(re,im,tw,65);
  {
    int lane=tid&63, wid=tid>>6;
    float s1=0.f;
    for (int t=tid;t<4096;t+=256) s1 += re[(t>>6)*65+(t&63)];
    float v=s1; for (int o=32;o>0;o>>=1) v+=__shfl_down(v,o);
    if (lane==0) red[wid]=v;
    __syncthreads();
    if (tid==0) shmu=(red[0]+red[1]+red[2]+red[3])*(sc*sc);  // mean of normalized lowpass
    __syncthreads();
    float mu=shmu, adc=0.f;
    for (int t=tid;t<4096;t+=256) adc += fabsf(re[(t>>6)*65+(t&63)]*sc - mu);
    v=adc; for (int o=32;o>0;o>>=1) v+=__shfl_down(v,o);
    if (lane==0) red[wid]=v;
    __syncthreads();
    if (tid==0) S[23]=(double)(red[0]+red[1]+red[2]+red[3]);
    __syncthreads();
  }
  // ---- imlp ----
  for (int t=tid;t<4096;t+=256){
    int a2=t>>6, b=t&63;
    int KR = b + ((b<32)?0:960);
    int KC = a2 + ((a2<32)?0:960);
    float2 v = F[(size_t)KC*1024+KR];
    float lr = lograd(b,a2,64);
    float m = cumlo(lr,4)*rc_cos(lr,1.f);
    if (t==0) m=0.f;
    re[a2*65+b]=v.x*m; im[a2*65+b]=v.y*m;
  }
  ifft2_lds<6>(re,im,tw,65);
  {
    float s2=0.f,s3=0.f,s4=0.f;
    float acc[41];
    #pragma unroll
    for (int k=0;k<41;k++) acc[k]=0.f;
    for (int p=tid;p<4096;p+=256){
      int y=p>>6, x=p&63;
      float m0u=re[y*65+x];
      float m0=m0u*sc, m02=m0*m0;
      s2+=m02; s3+=m02*m0; s4+=m02*m02;
      // LDS holds transposed spatial image -> apply dj to LDS-row, di to LDS-col
      #pragma unroll
      for (int dj=1;dj<=4;dj++)
        #pragma unroll
        for (int di=-4;di<=4;di++)
          acc[(dj-1)*9+di+4] += m0u * re[((y+dj)&63)*65 + ((x+di)&63)];
      #pragma unroll
      for (int di=0;di<=4;di++)
        acc[36+di] += m0u * re[y*65 + ((x+di)&63)];
    }
    #pragma unroll
    for (int k=0;k<41;k++) acc[k]*=sc*sc;
    float mom[3]={s2,s3,s4};
    blockAccumN<3>(S+36, mom, red);
    blockAccumN<41>(S+SL_ALP, acc, red);
  }
}

__global__ __launch_bounds__(256) void k_final(const double* __restrict__ S,
                                               const float* __restrict__ PB, float* out){
  __shared__ double SD[SL_TOT];
  __shared__ double sh[6];
  __shared__ double wrD[4][4];
  __shared__ float  wrF[2][4];
  const int tid = threadIdx.x;
  for (int k=tid;k<SL_TOT;k+=256){
    double v=0.0;
    #pragma unroll
    for (int r=0;r<REP;r++) v += S[(size_t)r*SL_TOT+k];
    SD[k]=v;
  }
  {
    int lane=tid&63, wid=tid>>6;
    double p0=PB[tid*8+0], p1=PB[tid*8+1], p2=PB[tid*8+2], p3=PB[tid*8+3];
    float pn=PB[tid*8+4], px=PB[tid*8+5];
    for (int o=32;o>0;o>>=1){ p0+=__shfl_down(p0,o); p1+=__shfl_down(p1,o); p2+=__shfl_down(p2,o); p3+=__shfl_down(p3,o); }
    if (lane==0){ wrD[0][wid]=p0; wrD[1][wid]=p1; wrD[2][wid]=p2; wrD[3][wid]=p3; }
    { float v=pn; for (int o=32;o>0;o>>=1) v=fminf(v,__shfl_down(v,o)); if(lane==0) wrF[0][wid]=v; }
    { float v=px; for (int o=32;o>0;o>>=1) v=fmaxf(v,__shfl_down(v,o)); if(lane==0) wrF[1][wid]=v; }
    __syncthreads();
    if (tid==0){
      for (int k=0;k<4;k++) sh[k]=wrD[k][0]+wrD[k][1]+wrD[k][2]+wrD[k][3];
      sh[4]=(double)fminf(fminf(wrF[0][0],wrF[0][1]),fminf(wrF[0][2],wrF[0][3]));
      sh[5]=(double)fmaxf(fmaxf(wrF[1][0],wrF[1][1]),fmaxf(wrF[1][2],wrF[1][3]));
    }
    __syncthreads();
  }
  const double npix[4]={1048576.0,262144.0,65536.0,16384.0};
  for (int e=tid; e<81*16; e+=256){
    int w=e>>4, s=(e>>2)&3, b=e&3;
    int i=w/9, j=w-i*9;
    int k=lagIdx(i-4,j-4);
    double n2=npix[s];
    double mu=SD[6+s*4+b]/n2;
    out[24+(w*4+s)*4+b]=(float)(SD[SL_ACE+(s*4+b)*41+k]/n2 - mu*mu);
  }
  for (int e=tid; e<81*4; e+=256){
    int w=e>>2, s=e&3;
    int i=w/9, j=w-i*9;
    int k=lagIdx(i-4,j-4);
    out[1330+w*5+s]=(float)(SD[SL_ACR+s*41+k]/(2.0*npix[s]));
  }
  for (int w=tid; w<81; w+=256){
    int i=w/9, j=w-i*9;
    int k=lagIdx(i-4,j-4);
    out[1330+w*5+4]=(float)(SD[SL_ALP+k]/4096.0);
  }
  // C0 / Cr0 (s<4)
  for (int e=tid; e<64; e+=256){
    int s=e>>4, i=(e>>2)&3, j=e&3;
    int a2=i<j?i:j, bb=i<j?j:i;
    int p=a2*(7-a2)/2+bb;
    double n2=npix[s];
    double Si=SD[6+s*4+i], Sj=SD[6+s*4+j];
    out[1735+(i*4+j)*5+s]=(float)((SD[40+s*20+p]-Si*Sj/n2)/n2);
    out[1879+(i*8+j)*5+s]=(float)(SD[40+s*20+10+p]/n2);
  }
  // Cx0 / Crx (s<3)
  for (int e=tid; e<48; e+=256){
    int s=e>>4, j=(e>>2)&3, i=e&3;
    double n2=npix[s];
    int pb=120+(s*4+j)*13;
    double Smj=SD[pb];
    double Si=SD[6+s*4+i];
    out[1815+(i*4+j)*4+s]=(float)((SD[pb+1+i]-Si*Smj/n2)/n2);
    out[2199+(i*8+j)*4+s]=(float)(SD[pb+5+i]/n2);
    out[2199+(i*8+(j+4))*4+s]=(float)(SD[pb+9+i]/n2);
  }
  for (int e=tid; e<20; e+=256){
    int i=e/5, j=e%5;
    out[2199+(i*8+j)*4+3]=(float)(SD[280+i*5+j]/16384.0);
  }
  for (int e=tid; e<25; e+=256){
    int i=e/5, j=e%5;
    int a2=i<j?i:j, bb=i<j?j:i;
    int p=a2*(9-a2)/2+bb;
    out[1879+(i*8+j)*5+4]=(float)(SD[300+p]/4096.0);
  }
  if (tid==0){
    const double N0=1048576.0;
    double sum=sh[0], s2=sh[1], s3=sh[2], s4=sh[3];
    double mean0=sum/N0;
    double var0=(s2 - sum*mean0)/(N0-1.0);
    double m3 = s3 - 3.0*mean0*s2 + 2.0*N0*mean0*mean0*mean0;
    double m4 = s4 - 4.0*mean0*s3 + 6.0*mean0*mean0*s2 - 3.0*N0*mean0*mean0*mean0*mean0;
    out[0]=(float)mean0; out[1]=(float)var0;
    out[2]=(float)((m3/N0)/(var0*sqrt(var0)));
    out[3]=(float)((m4/N0)/(var0*var0));
    out[4]=(float)sh[4]; out[5]=(float)sh[5];
    out[6]=(float)(SD[4]/N0);
    for (int s=0;s<4;s++) for (int b=0;b<4;b++) out[7+s*4+b]=(float)(SD[6+s*4+b]/npix[s]);
    out[23]=(float)(SD[23]/4096.0);
    for (int s=0;s<4;s++){
      double n2=npix[s];
      double vari=SD[24+s*3]/(2.0*n2);
      int ok=(vari/var0>1e-6);
      out[1320+s]= ok? (float)(0.5*(SD[25+s*3]/n2)/(vari*sqrt(vari))) : 0.f;
      out[1325+s]= ok? (float)(0.5*(SD[26+s*3]/n2)/(vari*vari)) : 3.f;
    }
    { double vari=SD[36]/4096.0; int ok=(vari/var0>1e-6);
      out[1324]= ok? (float)((SD[37]/4096.0)/(vari*sqrt(vari))) : 0.f;
      out[1329]= ok? (float)((SD[38]/4096.0)/(vari*vari)) : 3.f; }
    out[2455]=(float)(SD[5]/N0);
  }
}

// ---------------- host orchestration -----------------------------------------
static void launchB(int n, int nimg, const BArgs& a, hipStream_t st){
  switch(n){
    case 1024: k_fftB<1024><<<dim3(1024,nimg),fftT(1024),0,st>>>(a); break;
    case 512:  k_fftB<512 ><<<dim3(512 ,nimg),fftT(512 ),0,st>>>(a); break;
    case 256:  k_fftB<256 ><<<dim3(256 ,nimg),fftT(256 ),0,st>>>(a); break;
    case 128:  k_fftB<128 ><<<dim3(128 ,nimg),fftT(128 ),0,st>>>(a); break;
  }
}

extern "C" void kernel_launch(void* const* d_in, const int* in_sizes, int n_in,
                              void* d_out, int out_size, void* d_ws, size_t ws_size,
                              hipStream_t stream){
  const float* im = (const float*)d_in[0];
  float* out = (float*)d_out;
  char* w = (char*)d_ws;
  float2* F   = (float2*)w;                         // 8 MB: imdft^T
  float2* CA4 = (float2*)(w + ((size_t)8<<20));     // 32 MB: 4 bands
  float2* CC  = (float2*)(w + ((size_t)40<<20));    // 8 MB: unor
  float2* CB4 = (float2*)(w + ((size_t)48<<20));    // 16 MB: hi0 / parents / rp
  size_t off = (size_t)64<<20;
  double* S = (double*)(w+off);
  float* PB = (float*)(w+off+(size_t)REP*SL_TOT*8);

  k_init<<<40,256,0,stream>>>(S,out,2456);
  k_imgstats<<<256,256,0,stream>>>((const float4*)im,PB);

  // forward fft2 -> F^T
  { BArgs a{}; a.rsrc=im; a.dirsign=-1.f;
    a.img[0]=ImgD{nullptr,F,nullptr,1,0,0,0,1.f};
    launchB(1024,1,a,stream); }
  { TArgs t{}; t.base[0]=F; t.n=1024;
    k_trip<<<dim3(32,32,1),dim3(32,8),0,stream>>>(t); }
  { BArgs a{}; a.dirsign=-1.f;
    a.img[0]=ImgD{F,F,nullptr,0,0,0,0,1.f};
    launchB(1024,1,a,stream); }

  for (int s=0;s<4;s++){
    const int n=1024>>s, nt=n/32, n2=n*n, lg=10-s;
    const float inv=1.f/(float)n;
    const int nimg = (s==0)? 6 : 5;
    // pass1: bands + unor (+ hi0 at s=0)
    { BArgs a{}; a.F=F; a.dirsign=1.f;
      for (int b=0;b<4;b++) a.img[b]=ImgD{nullptr,CA4+(size_t)b*n2,nullptr,2,0,b,s,inv};
      a.img[4]=ImgD{nullptr,CC,nullptr,3,0,0,s,inv};
      if (s==0) a.img[5]=ImgD{nullptr,CB4,nullptr,4,0,0,0,inv};
      launchB(n,nimg,a,stream); }
    { TArgs t{}; t.n=n;
      for (int b=0;b<4;b++) t.base[b]=CA4+(size_t)b*n2;
      t.base[4]=CC; if (s==0) t.base[5]=CB4;
      k_trip<<<dim3(nt,nt,nimg),dim3(32,8),0,stream>>>(t); }
    { BArgs a{}; a.dirsign=1.f;
      for (int b=0;b<4;b++) a.img[b]=ImgD{CA4+(size_t)b*n2,CA4+(size_t)b*n2,S+6+s*4+b,0,2,0,0,inv};
      a.img[4]=ImgD{CC,CC,S+24+s*3,0,3,0,0,inv};
      if (s==0) a.img[5]=ImgD{CB4,nullptr,S+4,0,1,0,0,inv};
      launchB(n,nimg,a,stream); }
    k_gram<<<256,256,0,stream>>>(CA4,n2,S+40+s*20);
    { AArgs aa{}; aa.n=n; aa.lgn=lg; aa.nmag=4;
      for (int b=0;b<4;b++){ aa.base[b]=CA4+(size_t)b*n2; aa.slots[b]=S+SL_ACE+(size_t)(s*4+b)*41; }
      aa.base[4]=CC; aa.slots[4]=S+SL_ACR+(size_t)s*41;
      k_ac<<<dim3(n/64,n/64,5),256,0,stream>>>(aa); }
    if (s<3){
      const int nb = (s==0)? 2 : 4;
      for (int b0=0;b0<4;b0+=nb){
        { BArgs a{}; a.F=F; a.dirsign=1.f;
          for (int i=0;i<nb;i++) a.img[i]=ImgD{nullptr,CB4+(size_t)i*n2,nullptr,5,0,b0+i,s,inv};
          launchB(n,nb,a,stream); }
        { TArgs t{}; t.n=n;
          for (int i=0;i<nb;i++) t.base[i]=CB4+(size_t)i*n2;
          k_trip<<<dim3(nt,nt,nb),dim3(32,8),0,stream>>>(t); }
        { BArgs a{}; a.dirsign=1.f; a.aux=CA4;
          for (int i=0;i<nb;i++) a.img[i]=ImgD{CB4+(size_t)i*n2,nullptr,S+120+(size_t)(s*4+b0+i)*13,0,4,0,0,inv};
          launchB(n,nb,a,stream); }
      }
    } else {
      k_tail64<<<1,256,0,stream>>>(F,S);
      { BArgs a{}; a.F=F; a.dirsign=1.f;
        a.img[0]=ImgD{nullptr,CB4,nullptr,6,0,0,4,1.f/128.f};
        launchB(128,1,a,stream); }
      { TArgs t{}; t.base[0]=CB4; t.n=128;
        k_trip<<<dim3(4,4,1),dim3(32,8),0,stream>>>(t); }
      { BArgs a{}; a.dirsign=1.f;
        a.img[0]=ImgD{CB4,CB4,nullptr,0,0,0,0,1.f/128.f};
        launchB(128,1,a,stream); }
      k_crx3<<<64,256,0,stream>>>(CB4,CA4,S);
    }
  }
  k_final<<<1,256,0,stream>>>(S,PB,out);
  (void)in_sizes; (void)n_in; (void)out_size; (void)ws_size;
}

// Round 7
// 489.648 us; speedup vs baseline: 10.7123x; 1.0929x over previous
//
#include <hip/hip_runtime.h>

#define PI_F     3.14159265358979323846f
#define TWOPI_F  6.28318530717958647692f
#define HPI_F    1.57079632679489661923f

constexpr int fftT(int N){ return N>=512 ? 256 : (N/2 < 64 ? 64 : N/2); }

// S-slot layout (doubles), replicated REP times (replica stride SL_TOT)
#define SL_ACE 340          // 16 x 41
#define SL_ACR 996          // 4 x 41
#define SL_ALP 1160         // 41
#define SL_TOT 1280
#define REP 8

__device__ __forceinline__ float fcoord(int k, int n){
  int s = k ^ (n>>1);
  return (float)(s - (n>>1)) / (float)(n>>1);
}
__device__ __forceinline__ float lograd(int kr, int kc, int n){
  if (kr==0 && kc==0) return log2f(2.0f/(float)n);
  float x = fcoord(kc,n), y = fcoord(kr,n);
  return 0.5f*log2f(x*x+y*y);
}
__device__ __forceinline__ float rc_sin(float lr, float shift){
  float t = fminf(fmaxf(lr+shift,0.f),1.f); return __sinf(HPI_F*t);
}
__device__ __forceinline__ float rc_cos(float lr, float shift){
  float t = fminf(fmaxf(lr+shift,0.f),1.f); return __cosf(HPI_F*t);
}
// cumulative lowpass mask to reach scale s: prod_{m=0..s} rc_cos(lr, 1-m)
__device__ __forceinline__ float cumlo(float lr, int s){
  float cl = rc_cos(lr, 1.f);
  for (int m=1;m<=s;m++) cl *= rc_cos(lr, 1.f-(float)m);
  return cl;
}
__device__ __forceinline__ float bandmask(int kr, int kc, int n, int b){
  float x = fcoord(kc,n), y = fcoord(kr,n);
  float ang = atan2f(y,x);
  float lr = lograd(kr,kc,n);
  float him = rc_sin(lr,2.0f);
  float th = ang - 0.25f*PI_F*(float)b;
  float u = th + PI_F;
  u -= TWOPI_F*floorf(u*(1.0f/TWOPI_F));
  float thw = u - PI_F;
  float c = __cosf(th);
  float am = (fabsf(thw) < HPI_F) ? (1.7888543819998317f*c*c*c) : 0.0f;
  return am*him;
}
__device__ __forceinline__ int lagIdx(int di, int dj){
  if (dj < 0 || (dj==0 && di<0)){ di=-di; dj=-dj; }
  return dj==0 ? 36+di : (dj-1)*9 + (di+4);
}
__device__ __forceinline__ void atomAddD(double* p, double v){
  unsafeAtomicAdd(p, v);
}
template<int NS>
__device__ __forceinline__ void blockAccumN(double* base, const float* vals, float* red){
  const int lane = threadIdx.x & 63, wid = threadIdx.x >> 6;
  const int nw = (int)(blockDim.x >> 6);
  #pragma unroll
  for (int k=0;k<NS;k++){
    float v = vals[k];
    #pragma unroll
    for (int o=32;o>0;o>>=1) v += __shfl_down(v,o);
    if (lane==0) red[k*nw+wid]=v;
  }
  __syncthreads();
  const int rep = (int)((blockIdx.x ^ (blockIdx.y<<1) ^ (blockIdx.z<<2)) & 7) * SL_TOT;
  if ((int)threadIdx.x < NS){
    float s=0.f;
    for (int w2=0;w2<nw;w2++) s += red[(int)threadIdx.x*nw+w2];
    atomAddD(base+rep+(int)threadIdx.x,(double)s);
  }
  __syncthreads();
}

// ---------------- batched descriptor FFT -------------------------------------
// pre: 0 cplx slab, 1 real row, 2 band from F, 3 him from F, 4 hi0 from F,
//      5 padband from F, 6 padlp from F
// post: 0 store, 1 sum|x|,x^2, 2 store(re,mag)+summag, 3 store+moments, 4 parentred
struct ImgD { const float2* src; float2* dst; double* slots; int pre, post, b, ss; float scale; };
struct BArgs { ImgD img[6]; const float* rsrc; const float2* F; const float2* aux; float dirsign; };

#define TWI(k) ((k)+((k)>>4))

template<int N>
__global__ __launch_bounds__(fftT(N)) void k_fftB(BArgs a){
  constexpr int T = fftT(N);
  constexpr int LG = (N==1024)?10:(N==512)?9:(N==256)?8:(N==128)?7:6;
  __shared__ float2 sm[2][N];
  __shared__ float2 tw[N/2 + N/32];
  __shared__ float red[13*4];
  const ImgD d = a.img[blockIdx.y];
  const int row = blockIdx.x, tid = threadIdx.x;
  bool zrow=false;

  for (int k=tid;k<N/2;k+=T){
    float sn,cs; __sincosf(TWOPI_F*(float)k/(float)N,&sn,&cs);
    tw[TWI(k)]=make_float2(cs,sn);
  }

  switch(d.pre){
    case 0: {
      const float2* sp = d.src + (size_t)row*N;
      for (int i=tid;i<N;i+=T) sm[0][i]=sp[i];
    } break;
    case 1: {
      const float* rp = a.rsrc + (size_t)row*N;
      for (int i=tid;i<N;i+=T) sm[0][i]=make_float2(rp[i],0.f);
    } break;
    case 2: {
      const int KC = row + ((row < N/2)? 0 : (1024-N));
      const float2* Fr = a.F + (size_t)KC*1024;
      for (int i=tid;i<N;i+=T){
        int KR = i + ((i < N/2)? 0 : (1024-N));
        float2 v = Fr[KR];
        float lr = lograd(i,row,N);
        float m = cumlo(lr,d.ss)*bandmask(i,row,N,d.b);
        sm[0][i]=make_float2(-v.y*m, v.x*m);   // (-1j)^3 = +i
      }
    } break;
    case 3: {
      const int KC = row + ((row < N/2)? 0 : (1024-N));
      const float2* Fr = a.F + (size_t)KC*1024;
      for (int i=tid;i<N;i+=T){
        int KR = i + ((i < N/2)? 0 : (1024-N));
        float2 v = Fr[KR];
        float lr = lograd(i,row,N);
        float m = cumlo(lr,d.ss)*rc_sin(lr,2.f);
        sm[0][i]=make_float2(v.x*m, v.y*m);
      }
    } break;
    case 4: {
      const float2* Fr = a.F + (size_t)row*1024;
      for (int i=tid;i<N;i+=T){
        float2 v = Fr[i];
        float m = rc_sin(lograd(i,row,N),1.f);
        sm[0][i]=make_float2(v.x*m, v.y*m);
      }
    } break;
    case 5: case 6: {
      constexpr int M=N/2, Q=N/4;
      const int fi = (row<Q)? row : (row>=N-Q ? row-M : -1);
      if (fi<0){
        for (int i=tid;i<N;i+=T) sm[0][i]=make_float2(0.f,0.f);
        zrow=true;
      } else {
        const int KC = fi + ((fi < M/2)? 0 : (1024-M));
        const float2* Fr = a.F + (size_t)KC*1024;
        for (int i=tid;i<N;i+=T){
          int fj = (i<Q)? i : (i>=N-Q ? i-M : -1);
          float2 r = make_float2(0.f,0.f);
          if (fj>=0){
            int KR = fj + ((fj < M/2)? 0 : (1024-M));
            float2 v = Fr[KR];
            float lr = lograd(fj,fi,M);
            if (d.pre==5){
              float m = cumlo(lr,d.ss+1)*bandmask(fj,fi,M,d.b);
              r = make_float2(-v.y*m, v.x*m);
            } else {
              if (!(fi==0 && fj==0)){
                float m = cumlo(lr,4);
                r = make_float2(v.x*m, v.y*m);
              }
            }
          }
          sm[0][i]=r;
        }
      }
    } break;
  }

  int cur=0;
  if (!zrow){
    const float ds = a.dirsign;
    int ls2 = 0;
    // radix-4 stages
    for (; ls2+2<=LG; ls2+=2){
      const int Ns = 1<<ls2;
      __syncthreads();
      for (int j=tid; j<N/4; j+=T){
        const int m = j & (Ns-1);
        const int base = ((j>>ls2)<<(ls2+2)) + m;
        float2 x0 = sm[cur][j];
        float2 x1 = sm[cur][j+N/4];
        float2 x2 = sm[cur][j+N/2];
        float2 x3 = sm[cur][j+3*(N/4)];
        float2 w = tw[TWI(m<<(LG-2-ls2))];
        float w1x=w.x, w1y=ds*w.y;
        float w2x = w1x*w1x - w1y*w1y, w2y = 2.f*w1x*w1y;
        float w3x = w2x*w1x - w2y*w1y, w3y = w2x*w1y + w2y*w1x;
        float2 b = make_float2(x1.x*w1x - x1.y*w1y, x1.x*w1y + x1.y*w1x);
        float2 c = make_float2(x2.x*w2x - x2.y*w2y, x2.x*w2y + x2.y*w2x);
        float2 e = make_float2(x3.x*w3x - x3.y*w3y, x3.x*w3y + x3.y*w3x);
        float t0x=x0.x+c.x, t0y=x0.y+c.y;
        float t1x=x0.x-c.x, t1y=x0.y-c.y;
        float t2x=b.x+e.x,  t2y=b.y+e.y;
        float t3x=b.x-e.x,  t3y=b.y-e.y;
        float rtx=-ds*t3y,  rty=ds*t3x;      // (-i|+i)*t3 per direction
        sm[cur^1][base]          = make_float2(t0x+t2x, t0y+t2y);
        sm[cur^1][base+Ns]       = make_float2(t1x+rtx, t1y+rty);
        sm[cur^1][base+2*Ns]     = make_float2(t0x-t2x, t0y-t2y);
        sm[cur^1][base+3*Ns]     = make_float2(t1x-rtx, t1y-rty);
      }
      cur ^= 1;
    }
    if (LG & 1){
      const int ls = LG-1, Ns = 1<<ls;
      __syncthreads();
      for (int j=tid; j<N/2; j+=T){
        const int m = j & (Ns-1);
        const int base = ((j>>ls)<<(ls+1)) + m;
        float2 va = sm[cur][j];
        float2 vb = sm[cur][j+N/2];
        float2 w = tw[TWI(m)];
        float wy = ds*w.y;
        float2 bw = make_float2(vb.x*w.x - vb.y*wy, vb.x*wy + vb.y*w.x);
        sm[cur^1][base]    = make_float2(va.x+bw.x, va.y+bw.y);
        sm[cur^1][base+Ns] = make_float2(va.x-bw.x, va.y-bw.y);
      }
      cur ^= 1;
    }
  }
  __syncthreads();

  const float sc = d.scale;
  switch(d.post){
    case 0: {
      float2* dp = d.dst + (size_t)row*N;
      for (int i=tid;i<N;i+=T){ float2 v=sm[cur][i]; dp[i]=make_float2(v.x*sc,v.y*sc); }
    } break;
    case 1: {
      float a1=0.f,a2=0.f;
      for (int i=tid;i<N;i+=T){ float v=sm[cur][i].x*sc; a1+=fabsf(v); a2+=v*v; }
      float vals[2]={a1,a2};
      blockAccumN<2>(d.slots, vals, red);
    } break;
    case 2: {   // store (re, mag)
      float2* dp = d.dst + (size_t)row*N;
      float am=0.f;
      for (int i=tid;i<N;i+=T){
        float2 v=sm[cur][i]; v.x*=sc; v.y*=sc;
        float m = sqrtf(v.x*v.x+v.y*v.y);
        dp[i]=make_float2(v.x, m);
        am += m;
      }
      float vals[1]={am};
      blockAccumN<1>(d.slots, vals, red);
    } break;
    case 3: {
      float2* dp = d.dst + (size_t)row*N;
      float s2=0.f,s3=0.f,s4=0.f;
      for (int i=tid;i<N;i+=T){
        float2 v=sm[cur][i]; v.x*=sc; v.y*=sc; dp[i]=v;
        float x=v.x, x2=x*x; s2+=x2; s3+=x2*x; s4+=x2*x2;
      }
      float vals[3]={s2,s3,s4};
      blockAccumN<3>(d.slots, vals, red);
    } break;
    case 4: {   // parent reduction; aux bands hold (re, mag)
      const float2* B = a.aux;
      constexpr size_t N2 = (size_t)N*N;
      float acc[13];
      #pragma unroll
      for (int k=0;k<13;k++) acc[k]=0.f;
      for (int i=tid;i<N;i+=T){
        float2 p=sm[cur][i]; p.x*=sc; p.y*=sc;
        float m = sqrtf(p.x*p.x+p.y*p.y);
        float rp=0.f, ip=0.f;
        if (m>0.f){ rp=(p.y*p.y-p.x*p.x)/m; ip=2.f*p.x*p.y/m; }
        size_t pos = (size_t)row*N + i;
        acc[0]+=m;
        #pragma unroll
        for (int k=0;k<4;k++){
          float2 z = B[k*N2+pos];
          acc[1+k]+=z.y*m; acc[5+k]+=z.x*rp; acc[9+k]+=z.x*ip;
        }
      }
      blockAccumN<13>(d.slots, acc, red);
    } break;
  }
}

// multi-base in-place batched square transpose
struct TArgs { float2* base[6]; int n; };
__global__ void k_trip(TArgs t){
  int bi = blockIdx.x, bj = blockIdx.y;
  if (bj < bi) return;
  const int n = t.n;
  float2* img = t.base[blockIdx.z];
  __shared__ float2 t0[32][33], t1[32][33];
  int r0=bi*32, c0=bj*32;
  for (int dy=threadIdx.y; dy<32; dy+=8){
    t0[dy][threadIdx.x] = img[(size_t)(r0+dy)*n + c0 + threadIdx.x];
    if (bi!=bj) t1[dy][threadIdx.x] = img[(size_t)(c0+dy)*n + r0 + threadIdx.x];
  }
  __syncthreads();
  for (int dy=threadIdx.y; dy<32; dy+=8){
    img[(size_t)(c0+dy)*n + r0 + threadIdx.x] = t0[threadIdx.x][dy];
    if (bi!=bj) img[(size_t)(r0+dy)*n + c0 + threadIdx.x] = t1[threadIdx.x][dy];
  }
}

// multi-base direct circular autocorrelation (41 unique 9x9 lags)
// register-blocked: each thread owns a 16-wide strip; mag read from .y
struct AArgs { const float2* base[5]; double* slots[5]; int n, lgn, nmag; };
__global__ __launch_bounds__(256) void k_ac(AArgs a){
  __shared__ float t[72][76];
  __shared__ float red[41*4];
  const int z = blockIdx.z;
  const float2* img = a.base[z];
  const bool mag = z < a.nmag;
  const int n = a.n, lgn = a.lgn;
  const int ty0 = blockIdx.y*64, tx0 = blockIdx.x*64;
  for (int idx = threadIdx.x; idx < 72*72; idx += 256){
    int ly = idx/72, lx = idx-ly*72;
    int gy = (ty0 + ly - 4) & (n-1), gx = (tx0 + lx - 4) & (n-1);
    float2 v = img[((size_t)gy<<lgn) + gx];
    t[ly][lx] = mag ? v.y : v.x;
  }
  __syncthreads();
  float acc[41];
  #pragma unroll
  for (int k=0;k<41;k++) acc[k]=0.f;
  const int y  = (threadIdx.x>>2) + 4;
  const int x0 = (threadIdx.x&3)*16 + 4;
  float4 m0v[4];
  #pragma unroll
  for (int k=0;k<4;k++) m0v[k] = *(const float4*)&t[y][x0+k*4];
  float* m0 = (float*)m0v;
  #pragma unroll
  for (int di=-4; di<=4; ++di){
    float4 rv[5];
    #pragma unroll
    for (int k=0;k<5;k++) rv[k] = *(const float4*)&t[y+di][x0+k*4];
    float* r = (float*)rv;
    if (di>=0){
      float s=0.f;
      #pragma unroll
      for (int k=0;k<16;k++) s += m0[k]*r[k];
      acc[36+di]+=s;
    }
    #pragma unroll
    for (int dj=1;dj<=4;dj++){
      float s=0.f;
      #pragma unroll
      for (int k=0;k<16;k++) s += m0[k]*r[k+dj];
      acc[(dj-1)*9+di+4]+=s;
    }
  }
  blockAccumN<41>(a.slots[z], acc, red);
}

// ---------------- misc kernels ----------------------------------------------
__global__ void k_init(double* S, float* out, int nout){
  int i = blockIdx.x*blockDim.x + threadIdx.x;
  if (i < REP*SL_TOT) S[i]=0.0;
  if (i < nout) out[i]=0.f;
}
__global__ __launch_bounds__(256) void k_imgstats(const float4* __restrict__ x, float* PB){
  float s1=0.f,s2=0.f,s3=0.f,s4=0.f, mn=3.4e38f, mx=-3.4e38f;
  const int base = blockIdx.x*1024 + threadIdx.x;
  #pragma unroll
  for (int it=0; it<4; ++it){
    float4 v = x[base + it*256];
    float vs[4]={v.x,v.y,v.z,v.w};
    #pragma unroll
    for (int k=0;k<4;k++){
      float t=vs[k], t2=t*t;
      s1+=t; s2+=t2; s3+=t2*t; s4+=t2*t2;
      mn=fminf(mn,t); mx=fmaxf(mx,t);
    }
  }
  __shared__ float wr[6][4];
  int lane=threadIdx.x&63, wid=threadIdx.x>>6;
  float sums[4]={s1,s2,s3,s4};
  #pragma unroll
  for (int k=0;k<4;k++){
    float v=sums[k];
    for (int o=32;o>0;o>>=1) v+=__shfl_down(v,o);
    if (lane==0) wr[k][wid]=v;
  }
  { float v=mn; for (int o=32;o>0;o>>=1) v=fminf(v,__shfl_down(v,o)); if(lane==0) wr[4][wid]=v; }
  { float v=mx; for (int o=32;o>0;o>>=1) v=fmaxf(v,__shfl_down(v,o)); if(lane==0) wr[5][wid]=v; }
  __syncthreads();
  if (threadIdx.x<4)  PB[blockIdx.x*8+threadIdx.x] = wr[threadIdx.x][0]+wr[threadIdx.x][1]+wr[threadIdx.x][2]+wr[threadIdx.x][3];
  if (threadIdx.x==4) PB[blockIdx.x*8+4] = fminf(fminf(wr[4][0],wr[4][1]),fminf(wr[4][2],wr[4][3]));
  if (threadIdx.x==5) PB[blockIdx.x*8+5] = fmaxf(fmaxf(wr[5][0],wr[5][1]),fmaxf(wr[5][2],wr[5][3]));
}
__global__ void k_gram(const float2* __restrict__ B, int n2, double* slots){
  float p[20];
  #pragma unroll
  for (int i=0;i<20;i++) p[i]=0.f;
  int stride = gridDim.x*blockDim.x;
  for (int i=blockIdx.x*blockDim.x+threadIdx.x; i<n2; i+=stride){
    float2 z0=B[i], z1=B[i+(size_t)n2], z2=B[i+2*(size_t)n2], z3=B[i+3*(size_t)n2];
    float m0=z0.y, m1=z1.y, m2=z2.y, m3=z3.y;
    float r0=z0.x, r1=z1.x, r2=z2.x, r3=z3.x;
    p[0]+=m0*m0; p[1]+=m0*m1; p[2]+=m0*m2; p[3]+=m0*m3;
    p[4]+=m1*m1; p[5]+=m1*m2; p[6]+=m1*m3;
    p[7]+=m2*m2; p[8]+=m2*m3; p[9]+=m3*m3;
    p[10]+=r0*r0; p[11]+=r0*r1; p[12]+=r0*r2; p[13]+=r0*r3;
    p[14]+=r1*r1; p[15]+=r1*r2; p[16]+=r1*r3;
    p[17]+=r2*r2; p[18]+=r2*r3; p[19]+=r3*r3;
  }
  __shared__ float red[20*4];
  blockAccumN<20>(slots,p,red);
}
__global__ void k_crx3(const float2* __restrict__ RP, const float2* __restrict__ B3, double* S){
  float a[35];
  #pragma unroll
  for (int i=0;i<35;i++) a[i]=0.f;
  int stride = gridDim.x*blockDim.x;
  for (int idx=blockIdx.x*blockDim.x+threadIdx.x; idx<16384; idx+=stride){
    int u=idx>>7, v=idx&127;
    float P0=RP[idx].x;
    float P1=RP[(u<<7) | ((v-1)&127)].x;
    float P2=RP[(u<<7) | ((v+1)&127)].x;
    float P3=RP[(((u-1)&127)<<7) | v].x;
    float P4=RP[(((u+1)&127)<<7) | v].x;
    float P[5]={P0,P1,P2,P3,P4};
    float R[4];
    #pragma unroll
    for (int b=0;b<4;b++) R[b]=B3[b*16384 + (v<<7) + u].x;
    #pragma unroll
    for (int i=0;i<4;i++)
      #pragma unroll
      for (int j=0;j<5;j++) a[i*5+j]+=R[i]*P[j];
    int k=20;
    #pragma unroll
    for (int i=0;i<5;i++)
      #pragma unroll
      for (int j=i;j<5;j++){ a[k]+=P[i]*P[j]; k++; }
  }
  __shared__ float red[35*4];
  float lo[20], hi[15];
  #pragma unroll
  for (int k=0;k<20;k++) lo[k]=a[k];
  #pragma unroll
  for (int k=0;k<15;k++) hi[k]=a[20+k];
  blockAccumN<20>(S+280, lo, red);
  blockAccumN<15>(S+300, hi, red);
}

// in-place unnormalized inverse 2D FFT in LDS, separated planes, stride S
template<int LG>
__device__ void ifft2_lds(float* re, float* im, const float2* tw, int S){
  constexpr int N=1<<LG, H=N>>1;
  const int tid=threadIdx.x, T=256;
  for (int ls=LG-1; ls>=0; --ls){
    const int h=1<<ls;
    __syncthreads();
    for (int t=tid; t<N*H; t+=T){
      int r=t>>(LG-1), j=t&(H-1);
      int m=j&(h-1);
      int i0=r*S + ((j>>ls)<<(ls+1)) + m, i1=i0+h;
      float ar=re[i0], ai=im[i0], br=re[i1], bi=im[i1];
      re[i0]=ar+br; im[i0]=ai+bi;
      float dr=ar-br, di=ai-bi;
      float2 w=tw[m<<(LG-1-ls)];
      re[i1]=dr*w.x - di*w.y;
      im[i1]=dr*w.y + di*w.x;
    }
  }
  __syncthreads();
  for (int t=tid;t<N*N;t+=T){
    int r=t>>LG, j=t&(N-1);
    int jb=(int)(__brev((unsigned)j)>>(32-LG));
    if (j<jb){
      int p=r*S+j, q=r*S+jb;
      float x=re[p]; re[p]=re[q]; re[q]=x;
      x=im[p]; im[p]=im[q]; im[q]=x;
    }
  }
  for (int ls=LG-1; ls>=0; --ls){
    const int h=1<<ls;
    __syncthreads();
    for (int t=tid; t<N*H; t+=T){
      int c=t>>(LG-1), j=t&(H-1);
      int m=j&(h-1);
      int i0=(((j>>ls)<<(ls+1))+m)*S + c, i1=i0+h*S;
      float ar=re[i0], ai=im[i0], br=re[i1], bi=im[i1];
      re[i0]=ar+br; im[i0]=ai+bi;
      float dr=ar-br, di=ai-bi;
      float2 w=tw[m<<(LG-1-ls)];
      re[i1]=dr*w.x - di*w.y;
      im[i1]=dr*w.y + di*w.x;
    }
  }
  __syncthreads();
  for (int t=tid;t<N*N;t+=T){
    int c=t>>LG, j=t&(N-1);
    int jb=(int)(__brev((unsigned)j)>>(32-LG));
    if (j<jb){
      int p=j*S+c, q=jb*S+c;
      float x=re[p]; re[p]=re[q]; re[q]=x;
      x=im[p]; im[p]=im[q]; im[q]=x;
    }
  }
  __syncthreads();
}

// fused 64x64 tail: lowpass (absdev) + imlp (moments + 41-lag AC)
__global__ __launch_bounds__(256) void k_tail64(const float2* __restrict__ F, double* S){
  __shared__ float re[64*65];
  __shared__ float im[64*65];
  __shared__ float2 tw[32];
  __shared__ float red[41*4];
  __shared__ float shmu;
  const int tid=threadIdx.x;
  const float sc=1.f/4096.f;
  for (int k=tid;k<32;k+=256){
    float sn,cs; __sincosf(TWOPI_F*(float)k/64.f,&sn,&cs);
    tw[k]=make_float2(cs,sn);
  }
  // ---- lowpass ----
  for (int t=tid;t<4096;t+=256){
    int a2=t>>6, b=t&63;
    int KR = b + ((b<32)?0:960);
    int KC = a2 + ((a2<32)?0:960);
    float2 v = F[(size_t)KC*1024+KR];
    float m = cumlo(lograd(b,a2,64),4);
    re[a2*65+b]=v.x*m; im[a2*65+b]=v.y*m;
  }
  ifft2_lds<6>(re,im,tw,65);
  {
    int lane=tid&63, wid=tid>>6;
    float s1=0.f;
    for (int t=tid;t<4096;t+=256) s1 += re[(t>>6)*65+(t&63)];
    float v=s1; for (int o=32;o>0;o>>=1) v+=__shfl_down(v,o);
    if (lane==0) red[wid]=v;
    __syncthreads();
    if (tid==0) shmu=(red[0]+red[1]+red[2]+red[3])*(sc*sc);
    __syncthreads();
    float mu=shmu, adc=0.f;
    for (int t=tid;t<4096;t+=256) adc += fabsf(re[(t>>6)*65+(t&63)]*sc - mu);
    v=adc; for (int o=32;o>0;o>>=1) v+=__shfl_down(v,o);
    if (lane==0) red[wid]=v;
    __syncthreads();
    if (tid==0) S[23]=(double)(red[0]+red[1]+red[2]+red[3]);
    __syncthreads();
  }
  // ---- imlp ----
  for (int t=tid;t<4096;t+=256){
    int a2=t>>6, b=t&63;
    int KR = b + ((b<32)?0:960);
    int KC = a2 + ((a2<32)?0:960);
    float2 v = F[(size_t)KC*1024+KR];
    float lr = lograd(b,a2,64);
    float m = cumlo(lr,4)*rc_cos(lr,1.f);
    if (t==0) m=0.f;
    re[a2*65+b]=v.x*m; im[a2*65+b]=v.y*m;
  }
  ifft2_lds<6>(re,im,tw,65);
  {
    float s2=0.f,s3=0.f,s4=0.f;
    float acc[41];
    #pragma unroll
    for (int k=0;k<41;k++) acc[k]=0.f;
    for (int p=tid;p<4096;p+=256){
      int y=p>>6, x=p&63;
      float m0u=re[y*65+x];
      float m0=m0u*sc, m02=m0*m0;
      s2+=m02; s3+=m02*m0; s4+=m02*m02;
      #pragma unroll
      for (int dj=1;dj<=4;dj++)
        #pragma unroll
        for (int di=-4;di<=4;di++)
          acc[(dj-1)*9+di+4] += m0u * re[((y+dj)&63)*65 + ((x+di)&63)];
      #pragma unroll
      for (int di=0;di<=4;di++)
        acc[36+di] += m0u * re[y*65 + ((x+di)&63)];
    }
    #pragma unroll
    for (int k=0;k<41;k++) acc[k]*=sc*sc;
    float mom[3]={s2,s3,s4};
    blockAccumN<3>(S+36, mom, red);
    blockAccumN<41>(S+SL_ALP, acc, red);
  }
}

__global__ __launch_bounds__(256) void k_final(const double* __restrict__ S,
                                               const float* __restrict__ PB, float* out){
  __shared__ double SD[SL_TOT];
  __shared__ double sh[6];
  __shared__ double wrD[4][4];
  __shared__ float  wrF[2][4];
  const int tid = threadIdx.x;
  for (int k=tid;k<SL_TOT;k+=256){
    double v=0.0;
    #pragma unroll
    for (int r=0;r<REP;r++) v += S[(size_t)r*SL_TOT+k];
    SD[k]=v;
  }
  {
    int lane=tid&63, wid=tid>>6;
    double p0=PB[tid*8+0], p1=PB[tid*8+1], p2=PB[tid*8+2], p3=PB[tid*8+3];
    float pn=PB[tid*8+4], px=PB[tid*8+5];
    for (int o=32;o>0;o>>=1){ p0+=__shfl_down(p0,o); p1+=__shfl_down(p1,o); p2+=__shfl_down(p2,o); p3+=__shfl_down(p3,o); }
    if (lane==0){ wrD[0][wid]=p0; wrD[1][wid]=p1; wrD[2][wid]=p2; wrD[3][wid]=p3; }
    { float v=pn; for (int o=32;o>0;o>>=1) v=fminf(v,__shfl_down(v,o)); if(lane==0) wrF[0][wid]=v; }
    { float v=px; for (int o=32;o>0;o>>=1) v=fmaxf(v,__shfl_down(v,o)); if(lane==0) wrF[1][wid]=v; }
    __syncthreads();
    if (tid==0){
      for (int k=0;k<4;k++) sh[k]=wrD[k][0]+wrD[k][1]+wrD[k][2]+wrD[k][3];
      sh[4]=(double)fminf(fminf(wrF[0][0],wrF[0][1]),fminf(wrF[0][2],wrF[0][3]));
      sh[5]=(double)fmaxf(fmaxf(wrF[1][0],wrF[1][1]),fmaxf(wrF[1][2],wrF[1][3]));
    }
    __syncthreads();
  }
  const double npix[4]={1048576.0,262144.0,65536.0,16384.0};
  for (int e=tid; e<81*16; e+=256){
    int w=e>>4, s=(e>>2)&3, b=e&3;
    int i=w/9, j=w-i*9;
    int k=lagIdx(i-4,j-4);
    double n2=npix[s];
    double mu=SD[6+s*4+b]/n2;
    out[24+(w*4+s)*4+b]=(float)(SD[SL_ACE+(s*4+b)*41+k]/n2 - mu*mu);
  }
  for (int e=tid; e<81*4; e+=256){
    int w=e>>2, s=e&3;
    int i=w/9, j=w-i*9;
    int k=lagIdx(i-4,j-4);
    out[1330+w*5+s]=(float)(SD[SL_ACR+s*41+k]/(2.0*npix[s]));
  }
  for (int w=tid; w<81; w+=256){
    int i=w/9, j=w-i*9;
    int k=lagIdx(i-4,j-4);
    out[1330+w*5+4]=(float)(SD[SL_ALP+k]/4096.0);
  }
  for (int e=tid; e<64; e+=256){
    int s=e>>4, i=(e>>2)&3, j=e&3;
    int a2=i<j?i:j, bb=i<j?j:i;
    int p=a2*(7-a2)/2+bb;
    double n2=npix[s];
    double Si=SD[6+s*4+i], Sj=SD[6+s*4+j];
    out[1735+(i*4+j)*5+s]=(float)((SD[40+s*20+p]-Si*Sj/n2)/n2);
    out[1879+(i*8+j)*5+s]=(float)(SD[40+s*20+10+p]/n2);
  }
  for (int e=tid; e<48; e+=256){
    int s=e>>4, j=(e>>2)&3, i=e&3;
    double n2=npix[s];
    int pb=120+(s*4+j)*13;
    double Smj=SD[pb];
    double Si=SD[6+s*4+i];
    out[1815+(i*4+j)*4+s]=(float)((SD[pb+1+i]-Si*Smj/n2)/n2);
    out[2199+(i*8+j)*4+s]=(float)(SD[pb+5+i]/n2);
    out[2199+(i*8+(j+4))*4+s]=(float)(SD[pb+9+i]/n2);
  }
  for (int e=tid; e<20; e+=256){
    int i=e/5, j=e%5;
    out[2199+(i*8+j)*4+3]=(float)(SD[280+i*5+j]/16384.0);
  }
  for (int e=tid; e<25; e+=256){
    int i=e/5, j=e%5;
    int a2=i<j?i:j, bb=i<j?j:i;
    int p=a2*(9-a2)/2+bb;
    out[1879+(i*8+j)*5+4]=(float)(SD[300+p]/4096.0);
  }
  if (tid==0){
    const double N0=1048576.0;
    double sum=sh[0], s2=sh[1], s3=sh[2], s4=sh[3];
    double mean0=sum/N0;
    double var0=(s2 - sum*mean0)/(N0-1.0);
    double m3 = s3 - 3.0*mean0*s2 + 2.0*N0*mean0*mean0*mean0;
    double m4 = s4 - 4.0*mean0*s3 + 6.0*mean0*mean0*s2 - 3.0*N0*mean0*mean0*mean0*mean0;
    out[0]=(float)mean0; out[1]=(float)var0;
    out[2]=(float)((m3/N0)/(var0*sqrt(var0)));
    out[3]=(float)((m4/N0)/(var0*var0));
    out[4]=(float)sh[4]; out[5]=(float)sh[5];
    out[6]=(float)(SD[4]/N0);
    for (int s=0;s<4;s++) for (int b=0;b<4;b++) out[7+s*4+b]=(float)(SD[6+s*4+b]/npix[s]);
    out[23]=(float)(SD[23]/4096.0);
    for (int s=0;s<4;s++){
      double n2=npix[s];
      double vari=SD[24+s*3]/(2.0*n2);
      int ok=(vari/var0>1e-6);
      out[1320+s]= ok? (float)(0.5*(SD[25+s*3]/n2)/(vari*sqrt(vari))) : 0.f;
      out[1325+s]= ok? (float)(0.5*(SD[26+s*3]/n2)/(vari*vari)) : 3.f;
    }
    { double vari=SD[36]/4096.0; int ok=(vari/var0>1e-6);
      out[1324]= ok? (float)((SD[37]/4096.0)/(vari*sqrt(vari))) : 0.f;
      out[1329]= ok? (float)((SD[38]/4096.0)/(vari*vari)) : 3.f; }
    out[2455]=(float)(SD[5]/N0);
  }
}

// ---------------- host orchestration -----------------------------------------
static void launchB(int n, int nimg, const BArgs& a, hipStream_t st){
  switch(n){
    case 1024: k_fftB<1024><<<dim3(1024,nimg),fftT(1024),0,st>>>(a); break;
    case 512:  k_fftB<512 ><<<dim3(512 ,nimg),fftT(512 ),0,st>>>(a); break;
    case 256:  k_fftB<256 ><<<dim3(256 ,nimg),fftT(256 ),0,st>>>(a); break;
    case 128:  k_fftB<128 ><<<dim3(128 ,nimg),fftT(128 ),0,st>>>(a); break;
  }
}

extern "C" void kernel_launch(void* const* d_in, const int* in_sizes, int n_in,
                              void* d_out, int out_size, void* d_ws, size_t ws_size,
                              hipStream_t stream){
  const float* im = (const float*)d_in[0];
  float* out = (float*)d_out;
  char* w = (char*)d_ws;
  float2* F   = (float2*)w;                         // 8 MB: imdft^T
  float2* CA4 = (float2*)(w + ((size_t)8<<20));     // 32 MB: 4 bands
  float2* CC  = (float2*)(w + ((size_t)40<<20));    // 8 MB: unor
  float2* CB4 = (float2*)(w + ((size_t)48<<20));    // 16 MB: hi0 / parents / rp
  size_t off = (size_t)64<<20;
  double* S = (double*)(w+off);
  float* PB = (float*)(w+off+(size_t)REP*SL_TOT*8);

  k_init<<<40,256,0,stream>>>(S,out,2456);
  k_imgstats<<<256,256,0,stream>>>((const float4*)im,PB);

  // forward fft2 -> F^T
  { BArgs a{}; a.rsrc=im; a.dirsign=-1.f;
    a.img[0]=ImgD{nullptr,F,nullptr,1,0,0,0,1.f};
    launchB(1024,1,a,stream); }
  { TArgs t{}; t.base[0]=F; t.n=1024;
    k_trip<<<dim3(32,32,1),dim3(32,8),0,stream>>>(t); }
  { BArgs a{}; a.dirsign=-1.f;
    a.img[0]=ImgD{F,F,nullptr,0,0,0,0,1.f};
    launchB(1024,1,a,stream); }

  for (int s=0;s<4;s++){
    const int n=1024>>s, nt=n/32, n2=n*n, lg=10-s;
    const float inv=1.f/(float)n;
    const int nimg = (s==0)? 6 : 5;
    // pass1: bands + unor (+ hi0 at s=0)
    { BArgs a{}; a.F=F; a.dirsign=1.f;
      for (int b=0;b<4;b++) a.img[b]=ImgD{nullptr,CA4+(size_t)b*n2,nullptr,2,0,b,s,inv};
      a.img[4]=ImgD{nullptr,CC,nullptr,3,0,0,s,inv};
      if (s==0) a.img[5]=ImgD{nullptr,CB4,nullptr,4,0,0,0,inv};
      launchB(n,nimg,a,stream); }
    { TArgs t{}; t.n=n;
      for (int b=0;b<4;b++) t.base[b]=CA4+(size_t)b*n2;
      t.base[4]=CC; if (s==0) t.base[5]=CB4;
      k_trip<<<dim3(nt,nt,nimg),dim3(32,8),0,stream>>>(t); }
    { BArgs a{}; a.dirsign=1.f;
      for (int b=0;b<4;b++) a.img[b]=ImgD{CA4+(size_t)b*n2,CA4+(size_t)b*n2,S+6+s*4+b,0,2,0,0,inv};
      a.img[4]=ImgD{CC,CC,S+24+s*3,0,3,0,0,inv};
      if (s==0) a.img[5]=ImgD{CB4,nullptr,S+4,0,1,0,0,inv};
      launchB(n,nimg,a,stream); }
    k_gram<<<256,256,0,stream>>>(CA4,n2,S+40+s*20);
    { AArgs aa{}; aa.n=n; aa.lgn=lg; aa.nmag=4;
      for (int b=0;b<4;b++){ aa.base[b]=CA4+(size_t)b*n2; aa.slots[b]=S+SL_ACE+(size_t)(s*4+b)*41; }
      aa.base[4]=CC; aa.slots[4]=S+SL_ACR+(size_t)s*41;
      k_ac<<<dim3(n/64,n/64,5),256,0,stream>>>(aa); }
    if (s<3){
      const int nb = (s==0)? 2 : 4;
      for (int b0=0;b0<4;b0+=nb){
        { BArgs a{}; a.F=F; a.dirsign=1.f;
          for (int i=0;i<nb;i++) a.img[i]=ImgD{nullptr,CB4+(size_t)i*n2,nullptr,5,0,b0+i,s,inv};
          launchB(n,nb,a,stream); }
        { TArgs t{}; t.n=n;
          for (int i=0;i<nb;i++) t.base[i]=CB4+(size_t)i*n2;
          k_trip<<<dim3(nt,nt,nb),dim3(32,8),0,stream>>>(t); }
        { BArgs a{}; a.dirsign=1.f; a.aux=CA4;
          for (int i=0;i<nb;i++) a.img[i]=ImgD{CB4+(size_t)i*n2,nullptr,S+120+(size_t)(s*4+b0+i)*13,0,4,0,0,inv};
          launchB(n,nb,a,stream); }
      }
    } else {
      k_tail64<<<1,256,0,stream>>>(F,S);
      { BArgs a{}; a.F=F; a.dirsign=1.f;
        a.img[0]=ImgD{nullptr,CB4,nullptr,6,0,0,4,1.f/128.f};
        launchB(128,1,a,stream); }
      { TArgs t{}; t.base[0]=CB4; t.n=128;
        k_trip<<<dim3(4,4,1),dim3(32,8),0,stream>>>(t); }
      { BArgs a{}; a.dirsign=1.f;
        a.img[0]=ImgD{CB4,CB4,nullptr,0,0,0,0,1.f/128.f};
        launchB(128,1,a,stream); }
      k_crx3<<<64,256,0,stream>>>(CB4,CA4,S);
    }
  }
  k_final<<<1,256,0,stream>>>(S,PB,out);
  (void)in_sizes; (void)n_in; (void)out_size; (void)ws_size;
}